// Round 1
// baseline (3142.090 us; speedup 1.0000x reference)
//
#include <hip/hip_runtime.h>
#include <hip/hip_bf16.h>
#include <cstdint>

// ---------------------------------------------------------------------------
// DGCNN forward on MI355X. All math in f32; inputs auto-detected bf16/f32.
// ---------------------------------------------------------------------------

static constexpr int BB  = 8;     // batch
static constexpr int NN  = 1024;  // points
static constexpr int KNB = 20;    // neighbors
static constexpr float BNEPS = 1e-5f;

static constexpr int NIN = 25;

// cumulative float-element offsets of the converted inputs inside ws.
// order: x, W1^T, W2^T, W3^T, W4^T, W5^T, Wl1, Wl2, bl2, Wl3, bl3,
//        g1,b1,g2,b2,g3,b3,g4,b4,g5,b5,g6,b6,g7,b7
__constant__ int c_cum[NIN + 1] = {
    0, 24576, 24960, 33152, 49536, 115072, 639360,
    1687936, 1819008, 1819264, 1829504, 1829544, 1829608, 1829672, 1829736,
    1829800, 1829928, 1830056, 1830312, 1830568, 1831592, 1832616, 1833128,
    1833640, 1833896, 1834152};
// transpose meta: W stored [O][I] in input, we store WT[I][O]. O==0 -> copy.
__constant__ int c_trO[NIN] = {0, 64, 64, 128, 256, 1024, 0, 0, 0, 0, 0,
                               0, 0, 0, 0, 0, 0, 0, 0, 0, 0, 0, 0, 0, 0};
__constant__ int c_trI[NIN] = {0, 6, 128, 128, 256, 512, 0, 0, 0, 0, 0,
                               0, 0, 0, 0, 0, 0, 0, 0, 0, 0, 0, 0, 0, 0};

// host-side ws float offsets (match c_cum for inputs)
enum : int {
  XIN = 0, WT1 = 24576, WT2 = 24960, WT3 = 33152, WT4 = 49536, WT5 = 115072,
  WL1 = 639360, WL2 = 1687936, BL2o = 1819008, WL3 = 1819264, BL3o = 1829504,
  G1 = 1829544, B1o = 1829608, G2 = 1829672, B2o = 1829736,
  G3 = 1829800, B3o = 1829928, G4 = 1830056, B4o = 1830312,
  G5 = 1830568, B5o = 1831592, G6 = 1832616, B6o = 1833128,
  G7 = 1833640, B7o = 1833896,
  XXo = 1834240,        // 8192 f
  IDXo = 1842432,       // 163840 i32
  HCATo = 2006272,      // 8*512*1024 f
  STATSo = 6200576,     // 5 layers * 4096 f (sum, sumsq, scale, shift)
  ZMAXo = 6221056,      // 8192 u32 (encoded max)
  ZSUMo = 6229248,      // 8192 f
  Z2048o = 6237440,     // 8*2048 f
  Z1o = 6253824,        // 8*512 f
  Z2o = 6257920,        // 8*256 f
  FLAGSo = 6259968      // 32 i32
};
static constexpr int TOTAL_IN = 1834152;

struct Ptrs { const void* p[NIN]; };

__device__ __forceinline__ unsigned enc_f32(float x) {
  unsigned u = __float_as_uint(x);
  return (u & 0x80000000u) ? ~u : (u | 0x80000000u);
}
__device__ __forceinline__ float dec_f32(unsigned u) {
  unsigned b = (u & 0x80000000u) ? (u & 0x7FFFFFFFu) : ~u;
  return __uint_as_float(b);
}
__device__ __forceinline__ float lrelu(float y) { return (y < 0.f) ? 0.2f * y : y; }

// ---------------------------------------------------------------------------
// dtype detection: flag 0 = f32, 1 = bf16, 2 = all-zero (write zeros)
// ---------------------------------------------------------------------------
__global__ void detect_kernel(Ptrs ptrs, int* __restrict__ flags) {
  const int i = blockIdx.x;
  const unsigned* p = (const unsigned*)ptrs.p[i];
  const int n = c_cum[i + 1] - c_cum[i];
  int words = n >> 1; if (words > 64) words = 64;
  const int t = threadIdx.x;
  unsigned w = (t < words) ? p[t] : 0u;
  bool nz = (w != 0u);
  unsigned e = (w >> 7) & 0xFFu;   // exponent field of the LOW half as bf16
  bool pl = nz && (e >= 96u) && (e <= 140u);
  unsigned long long mnz = __ballot(nz);
  unsigned long long mpl = __ballot(pl);
  if (t == 0) {
    int cnz = __popcll(mnz), cpl = __popcll(mpl);
    flags[i] = (cnz == 0) ? 2 : ((2 * cpl > words) ? 1 : 0);
  }
}

__global__ void globalflag_kernel(int* __restrict__ flags) {
  int anyf32 = 0, anybf = 0;
  for (int i = 0; i < NIN; ++i) {
    if (flags[i] == 0) anyf32 = 1;
    if (flags[i] == 1) anybf = 1;
  }
  flags[NIN] = (anybf && !anyf32) ? 1 : 0;   // output dtype
}

// convert (and transpose weight matrices) into f32 ws
__global__ void convert_kernel(Ptrs ptrs, const int* __restrict__ flags,
                               float* __restrict__ ws) {
  const int e = blockIdx.x * 256 + threadIdx.x;
  if (e >= TOTAL_IN) return;
  int i = 0;
  while (e >= c_cum[i + 1]) ++i;
  const int el = e - c_cum[i];
  int src;
  const int O = c_trO[i];
  if (O > 0) {
    const int I = c_trI[i];
    const int o = el % O, ii = el / O;
    src = o * I + ii;
  } else src = el;
  float v;
  const int fl = flags[i];
  if (fl == 2) v = 0.f;
  else if (fl == 1) {
    const unsigned short u = ((const unsigned short*)ptrs.p[i])[src];
    v = __uint_as_float(((unsigned)u) << 16);
  } else v = ((const float*)ptrs.p[i])[src];
  ws[e] = v;
}

__global__ void zero_kernel(float* __restrict__ p, int n) {
  const int i = blockIdx.x * 256 + threadIdx.x;
  if (i < n) p[i] = 0.f;
}

// ---------------------------------------------------------------------------
// xx[b][n] = sum_c x[b][c][n]^2
// ---------------------------------------------------------------------------
__global__ void xx_kernel(const float* __restrict__ xbase, int bstr, int C,
                          float* __restrict__ xx) {
  const int i = blockIdx.x * 256 + threadIdx.x;
  if (i >= BB * NN) return;
  const int b = i >> 10, n = i & 1023;
  const float* xb = xbase + (size_t)b * bstr;
  float s = 0.f;
  for (int c = 0; c < C; ++c) { const float v = xb[c * NN + n]; s = fmaf(v, v, s); }
  xx[i] = s;
}

// ---------------------------------------------------------------------------
// kNN: one block per (b,n); distances in LDS; 20 rounds of argmax
// (tie -> smaller index, matching jax.lax.top_k)
// ---------------------------------------------------------------------------
template <int C>
__global__ __launch_bounds__(256) void knn_kernel(const float* __restrict__ xbase,
                                                  int bstr,
                                                  const float* __restrict__ xx,
                                                  int* __restrict__ idxb) {
  __shared__ __align__(16) float s_d[NN];
  __shared__ float s_ctr[C];
  __shared__ float s_rv[4];
  __shared__ int s_ri[4];
  const int t = threadIdx.x;
  const int p = blockIdx.x;
  const int b = p >> 10, n = p & 1023;
  const float* xb = xbase + (size_t)b * bstr;
  if (t < C) s_ctr[t] = xb[t * NN + n];
  __syncthreads();
  {
    const int m0 = t * 4;
    float4 dot = make_float4(0.f, 0.f, 0.f, 0.f);
    for (int c = 0; c < C; ++c) {
      const float4 xv = *(const float4*)&xb[c * NN + m0];
      const float cv = s_ctr[c];
      dot.x = fmaf(cv, xv.x, dot.x);
      dot.y = fmaf(cv, xv.y, dot.y);
      dot.z = fmaf(cv, xv.z, dot.z);
      dot.w = fmaf(cv, xv.w, dot.w);
    }
    const float xxn = xx[p];
    const float4 xxm = *(const float4*)&xx[(b << 10) + m0];
    float4 dd;
    dd.x = 2.f * dot.x - xxn - xxm.x;
    dd.y = 2.f * dot.y - xxn - xxm.y;
    dd.z = 2.f * dot.z - xxn - xxm.z;
    dd.w = 2.f * dot.w - xxn - xxm.w;
    *(float4*)&s_d[m0] = dd;
  }
  __syncthreads();
  for (int kk = 0; kk < KNB; ++kk) {
    const int m0 = t * 4;
    const float4 dv = *(const float4*)&s_d[m0];
    float bv = dv.x; int bi = m0;
    if (dv.y > bv) { bv = dv.y; bi = m0 + 1; }
    if (dv.z > bv) { bv = dv.z; bi = m0 + 2; }
    if (dv.w > bv) { bv = dv.w; bi = m0 + 3; }
    for (int off = 32; off > 0; off >>= 1) {
      const float v2 = __shfl_down(bv, off, 64);
      const int i2 = __shfl_down(bi, off, 64);
      if (v2 > bv || (v2 == bv && i2 < bi)) { bv = v2; bi = i2; }
    }
    if ((t & 63) == 0) { s_rv[t >> 6] = bv; s_ri[t >> 6] = bi; }
    __syncthreads();
    if (t == 0) {
      float v = s_rv[0]; int i0 = s_ri[0];
      for (int w = 1; w < 4; ++w)
        if (s_rv[w] > v || (s_rv[w] == v && s_ri[w] < i0)) { v = s_rv[w]; i0 = s_ri[w]; }
      idxb[p * KNB + kk] = i0;
      s_d[i0] = -3.4e38f;
    }
    __syncthreads();
  }
}

// ---------------------------------------------------------------------------
// edge-conv (1x1 conv over [nb-ctr, ctr]) MODE 0: BN stats, MODE 1: BN+lrelu+max_k
// WT layout: [2C][COUT]. nbm LDS layout: [KNB][C].
// ---------------------------------------------------------------------------
template <int C, int COUT, int MODE>
__global__ __launch_bounds__(256) void conv2d_kernel(
    const float* __restrict__ xbase, int bstr, const int* __restrict__ idxb,
    const float* __restrict__ WT, float* __restrict__ stats,
    float* __restrict__ hout) {
  constexpr int G = 256 / COUT;
  constexpr int NPER = KNB / G;
  __shared__ __align__(16) float s_nbm[KNB * C];
  __shared__ float s_ctr[C];
  __shared__ float s_wc[COUT];
  __shared__ int s_idx[KNB];
  __shared__ float s_red[256];
  const int t = threadIdx.x;
  const int o = t % COUT, rep = t / COUT;
  float sc = 0.f, sh = 0.f;
  if (MODE == 1) { sc = stats[2048 + o]; sh = stats[3072 + o]; }
  float s1 = 0.f, s2 = 0.f;
  for (int p = blockIdx.x; p < BB * NN; p += gridDim.x) {
    const int b = p >> 10, n = p & 1023;
    const float* xb = xbase + (size_t)b * bstr;
    if (t < C) s_ctr[t] = xb[t * NN + n];
    if (t >= 224 && t < 224 + KNB) s_idx[t - 224] = idxb[p * KNB + (t - 224)];
    __syncthreads();
    for (int i = t; i < KNB * C; i += 256) {
      const int kk = i / C, c = i - kk * C;
      s_nbm[i] = xb[c * NN + s_idx[kk]] - s_ctr[c];
    }
    if (t < COUT) {
      float s = 0.f;
      for (int c = 0; c < C; ++c) s = fmaf(WT[(C + c) * COUT + t], s_ctr[c], s);
      s_wc[t] = s;
    }
    __syncthreads();
    float acc[NPER];
#pragma unroll
    for (int j = 0; j < NPER; ++j) acc[j] = 0.f;
    if constexpr ((C & 3) == 0) {
      for (int c = 0; c < C; c += 4) {
        const float w0 = WT[(c + 0) * COUT + o];
        const float w1 = WT[(c + 1) * COUT + o];
        const float w2 = WT[(c + 2) * COUT + o];
        const float w3 = WT[(c + 3) * COUT + o];
#pragma unroll
        for (int j = 0; j < NPER; ++j) {
          const float4 nb = *(const float4*)&s_nbm[(rep + j * G) * C + c];
          float a = acc[j];
          a = fmaf(w0, nb.x, a);
          a = fmaf(w1, nb.y, a);
          a = fmaf(w2, nb.z, a);
          a = fmaf(w3, nb.w, a);
          acc[j] = a;
        }
      }
    } else {
      for (int c = 0; c < C; ++c) {
        const float w = WT[c * COUT + o];
#pragma unroll
        for (int j = 0; j < NPER; ++j)
          acc[j] = fmaf(w, s_nbm[(rep + j * G) * C + c], acc[j]);
      }
    }
    const float wc = s_wc[o];
    if (MODE == 0) {
#pragma unroll
      for (int j = 0; j < NPER; ++j) {
        const float y = acc[j] + wc;
        s1 += y; s2 = fmaf(y, y, s2);
      }
      __syncthreads();
    } else {
      float mx = -3.4e38f;
#pragma unroll
      for (int j = 0; j < NPER; ++j) {
        const float y = lrelu(fmaf(sc, acc[j] + wc, sh));
        mx = fmaxf(mx, y);
      }
      s_red[t] = mx;
      __syncthreads();
      if (t < COUT) {
        float m = s_red[t];
        for (int r = 1; r < G; ++r) m = fmaxf(m, s_red[t + r * COUT]);
        hout[(size_t)b * (512 * 1024) + t * NN + n] = m;
      }
      __syncthreads();
    }
  }
  if (MODE == 0) {
    s_red[t] = s1; __syncthreads();
    if (t < COUT) {
      float s = s_red[t];
      for (int r = 1; r < G; ++r) s += s_red[t + r * COUT];
      atomicAdd(&stats[t], s);
    }
    __syncthreads();
    s_red[t] = s2; __syncthreads();
    if (t < COUT) {
      float s = s_red[t];
      for (int r = 1; r < G; ++r) s += s_red[t + r * COUT];
      atomicAdd(&stats[1024 + t], s);
    }
  }
}

// ---------------------------------------------------------------------------
// finalize BN: scale = g*rsqrt(var+eps), shift = b - mean*scale
// ---------------------------------------------------------------------------
__global__ void bn_finalize_kernel(float* __restrict__ stats,
                                   const float* __restrict__ g,
                                   const float* __restrict__ bb, int cout,
                                   float inv_cnt) {
  const int o = blockIdx.x * 256 + threadIdx.x;
  if (o >= cout) return;
  const float mean = stats[o] * inv_cnt;
  const float var = stats[1024 + o] * inv_cnt - mean * mean;
  const float s = g[o] * rsqrtf(var + BNEPS);
  stats[2048 + o] = s;
  stats[3072 + o] = bb[o] - mean * s;
}

// ---------------------------------------------------------------------------
// conv1d 512->1024 over hcat. grid 1024 = ot(4) x b(8) x nt(32).
// MODE 0: stats; MODE 1: BN+lrelu + atomic max/sum pooling over n.
// ---------------------------------------------------------------------------
template <int MODE>
__global__ __launch_bounds__(256) void conv1d_kernel(
    const float* __restrict__ hcat, const float* __restrict__ WT5,
    float* __restrict__ stats, unsigned* __restrict__ zmax,
    float* __restrict__ zsum) {
  __shared__ __align__(16) float s_h[64 * 32];
  const int t = threadIdx.x;
  const int bx = blockIdx.x;
  const int ot = bx & 3;
  const int b = (bx >> 2) & 7;
  const int nt = bx >> 5;
  const int n0 = nt * 32;
  const int o = ot * 256 + t;
  const float* hb = hcat + (size_t)b * (512 * 1024);
  float acc[32];
#pragma unroll
  for (int j = 0; j < 32; ++j) acc[j] = 0.f;
  for (int cc = 0; cc < 512; cc += 64) {
    for (int i = t; i < 64 * 32; i += 256) {
      const int c = i >> 5, nn2 = i & 31;
      s_h[i] = hb[(cc + c) * NN + n0 + nn2];
    }
    __syncthreads();
    for (int c = 0; c < 64; ++c) {
      const float w = WT5[(cc + c) * 1024 + o];
      const float4* hv = (const float4*)(s_h + c * 32);
#pragma unroll
      for (int q = 0; q < 8; ++q) {
        const float4 h4 = hv[q];
        acc[q * 4 + 0] = fmaf(w, h4.x, acc[q * 4 + 0]);
        acc[q * 4 + 1] = fmaf(w, h4.y, acc[q * 4 + 1]);
        acc[q * 4 + 2] = fmaf(w, h4.z, acc[q * 4 + 2]);
        acc[q * 4 + 3] = fmaf(w, h4.w, acc[q * 4 + 3]);
      }
    }
    __syncthreads();
  }
  if (MODE == 0) {
    float s1 = 0.f, s2 = 0.f;
#pragma unroll
    for (int j = 0; j < 32; ++j) { s1 += acc[j]; s2 = fmaf(acc[j], acc[j], s2); }
    atomicAdd(&stats[o], s1);
    atomicAdd(&stats[1024 + o], s2);
  } else {
    const float sc = stats[2048 + o], sh = stats[3072 + o];
    float mx = -3.4e38f, sm = 0.f;
#pragma unroll
    for (int j = 0; j < 32; ++j) {
      const float y = lrelu(fmaf(sc, acc[j], sh));
      mx = fmaxf(mx, y);
      sm += y;
    }
    atomicMax(&zmax[(b << 10) + o], enc_f32(mx));
    atomicAdd(&zsum[(b << 10) + o], sm);
  }
}

__global__ void zfin_kernel(const unsigned* __restrict__ zmax,
                            const float* __restrict__ zsum,
                            float* __restrict__ z) {
  const int i = blockIdx.x * 256 + threadIdx.x;
  if (i >= BB * 1024) return;
  const int b = i >> 10, o = i & 1023;
  z[b * 2048 + o] = dec_f32(zmax[i]);
  z[b * 2048 + 1024 + o] = zsum[i] * (1.f / 1024.f);
}

// ---------------------------------------------------------------------------
// MLP layer with batch-of-8 BN + lrelu fused. One block per output feature.
// ---------------------------------------------------------------------------
__global__ __launch_bounds__(256) void mlp_kernel(
    const float* __restrict__ zin, const float* __restrict__ W,
    const float* __restrict__ bias, const float* __restrict__ g,
    const float* __restrict__ bb, int kin, float* __restrict__ out, int O) {
  __shared__ float s_red[256];
  __shared__ float s_y[8];
  const int t = threadIdx.x;
  const int o = blockIdx.x;
  float acc[8];
#pragma unroll
  for (int b = 0; b < 8; ++b) acc[b] = 0.f;
  for (int c = t; c < kin; c += 256) {
    const float w = W[(size_t)o * kin + c];
#pragma unroll
    for (int b = 0; b < 8; ++b) acc[b] = fmaf(w, zin[b * kin + c], acc[b]);
  }
  for (int b = 0; b < 8; ++b) {
    s_red[t] = acc[b];
    __syncthreads();
    for (int s = 128; s > 0; s >>= 1) {
      if (t < s) s_red[t] += s_red[t + s];
      __syncthreads();
    }
    if (t == 0) s_y[b] = s_red[0] + (bias ? bias[o] : 0.f);
    __syncthreads();
  }
  if (t == 0) {
    float m = 0.f;
    for (int b = 0; b < 8; ++b) m += s_y[b];
    m *= 0.125f;
    float v = 0.f;
    for (int b = 0; b < 8; ++b) { const float d = s_y[b] - m; v = fmaf(d, d, v); }
    v *= 0.125f;
    const float s = g[o] * rsqrtf(v + BNEPS);
    const float sh = bb[o] - m * s;
    for (int b = 0; b < 8; ++b) out[b * O + o] = lrelu(fmaf(s, s_y[b], sh));
  }
}

// final: out = z2 @ Wl3^T + bl3, written in detected output dtype
__global__ void final_kernel(const float* __restrict__ z2,
                             const float* __restrict__ Wl3,
                             const float* __restrict__ bl3,
                             const int* __restrict__ flags, void* out) {
  const int j = blockIdx.x * 256 + threadIdx.x;
  if (j >= 320) return;
  const int b = j / 40, o = j - b * 40;
  float s = bl3[o];
  for (int c = 0; c < 256; ++c) s = fmaf(z2[b * 256 + c], Wl3[o * 256 + c], s);
  if (flags[NIN] == 1) ((__hip_bfloat16*)out)[j] = __float2bfloat16(s);
  else ((float*)out)[j] = s;
}

// ---------------------------------------------------------------------------
extern "C" void kernel_launch(void* const* d_in, const int* in_sizes, int n_in,
                              void* d_out, int out_size, void* d_ws,
                              size_t ws_size, hipStream_t stream) {
  (void)in_sizes; (void)n_in; (void)out_size; (void)ws_size;
  float* wsf = reinterpret_cast<float*>(d_ws);
  int* flags = reinterpret_cast<int*>(wsf + FLAGSo);
  int* idxb = reinterpret_cast<int*>(wsf + IDXo);
  float* xx = wsf + XXo;
  float* hcat = wsf + HCATo;
  unsigned* zmax = reinterpret_cast<unsigned*>(wsf + ZMAXo);
  float* zsum = wsf + ZSUMo;

  Ptrs ptrs;
  for (int i = 0; i < NIN; ++i) ptrs.p[i] = d_in[i];

  detect_kernel<<<NIN, 64, 0, stream>>>(ptrs, flags);
  globalflag_kernel<<<1, 1, 0, stream>>>(flags);
  convert_kernel<<<(TOTAL_IN + 255) / 256, 256, 0, stream>>>(ptrs, flags, wsf);
  zero_kernel<<<144, 256, 0, stream>>>(wsf + STATSo, 36864);

  const float inv2d = 1.f / (8.f * 1024.f * 20.f);

  // ---- stage 1 (input x, C=3) ----
  xx_kernel<<<32, 256, 0, stream>>>(wsf + XIN, 3 * NN, 3, xx);
  knn_kernel<3><<<BB * NN, 256, 0, stream>>>(wsf + XIN, 3 * NN, xx, idxb);
  conv2d_kernel<3, 64, 0><<<512, 256, 0, stream>>>(wsf + XIN, 3 * NN, idxb,
      wsf + WT1, wsf + STATSo + 0 * 4096, hcat);
  bn_finalize_kernel<<<4, 256, 0, stream>>>(wsf + STATSo + 0 * 4096,
      wsf + G1, wsf + B1o, 64, inv2d);
  conv2d_kernel<3, 64, 1><<<512, 256, 0, stream>>>(wsf + XIN, 3 * NN, idxb,
      wsf + WT1, wsf + STATSo + 0 * 4096, hcat + 0 * NN);

  // ---- stage 2 (input x1 = hcat ch 0..63) ----
  xx_kernel<<<32, 256, 0, stream>>>(hcat, 512 * NN, 64, xx);
  knn_kernel<64><<<BB * NN, 256, 0, stream>>>(hcat, 512 * NN, xx, idxb);
  conv2d_kernel<64, 64, 0><<<512, 256, 0, stream>>>(hcat, 512 * NN, idxb,
      wsf + WT2, wsf + STATSo + 1 * 4096, hcat);
  bn_finalize_kernel<<<4, 256, 0, stream>>>(wsf + STATSo + 1 * 4096,
      wsf + G2, wsf + B2o, 64, inv2d);
  conv2d_kernel<64, 64, 1><<<512, 256, 0, stream>>>(hcat, 512 * NN, idxb,
      wsf + WT2, wsf + STATSo + 1 * 4096, hcat + 64 * NN);

  // ---- stage 3 (input x2 = hcat ch 64..127) ----
  xx_kernel<<<32, 256, 0, stream>>>(hcat + 64 * NN, 512 * NN, 64, xx);
  knn_kernel<64><<<BB * NN, 256, 0, stream>>>(hcat + 64 * NN, 512 * NN, xx, idxb);
  conv2d_kernel<64, 128, 0><<<512, 256, 0, stream>>>(hcat + 64 * NN, 512 * NN,
      idxb, wsf + WT3, wsf + STATSo + 2 * 4096, hcat);
  bn_finalize_kernel<<<4, 256, 0, stream>>>(wsf + STATSo + 2 * 4096,
      wsf + G3, wsf + B3o, 128, inv2d);
  conv2d_kernel<64, 128, 1><<<512, 256, 0, stream>>>(hcat + 64 * NN, 512 * NN,
      idxb, wsf + WT3, wsf + STATSo + 2 * 4096, hcat + 128 * NN);

  // ---- stage 4 (input x3 = hcat ch 128..255, C=128) ----
  xx_kernel<<<32, 256, 0, stream>>>(hcat + 128 * NN, 512 * NN, 128, xx);
  knn_kernel<128><<<BB * NN, 256, 0, stream>>>(hcat + 128 * NN, 512 * NN, xx, idxb);
  conv2d_kernel<128, 256, 0><<<512, 256, 0, stream>>>(hcat + 128 * NN, 512 * NN,
      idxb, wsf + WT4, wsf + STATSo + 3 * 4096, hcat);
  bn_finalize_kernel<<<4, 256, 0, stream>>>(wsf + STATSo + 3 * 4096,
      wsf + G4, wsf + B4o, 256, inv2d);
  conv2d_kernel<128, 256, 1><<<512, 256, 0, stream>>>(hcat + 128 * NN, 512 * NN,
      idxb, wsf + WT4, wsf + STATSo + 3 * 4096, hcat + 256 * NN);

  // ---- conv1d 512->1024 + pooling ----
  conv1d_kernel<0><<<1024, 256, 0, stream>>>(hcat, wsf + WT5,
      wsf + STATSo + 4 * 4096, zmax, zsum);
  bn_finalize_kernel<<<4, 256, 0, stream>>>(wsf + STATSo + 4 * 4096,
      wsf + G5, wsf + B5o, 1024, 1.f / 8192.f);
  conv1d_kernel<1><<<1024, 256, 0, stream>>>(hcat, wsf + WT5,
      wsf + STATSo + 4 * 4096, zmax, zsum);
  zfin_kernel<<<32, 256, 0, stream>>>(zmax, zsum, wsf + Z2048o);

  // ---- MLP head ----
  mlp_kernel<<<512, 256, 0, stream>>>(wsf + Z2048o, wsf + WL1, nullptr,
      wsf + G6, wsf + B6o, 2048, wsf + Z1o, 512);
  mlp_kernel<<<256, 256, 0, stream>>>(wsf + Z1o, wsf + WL2, wsf + BL2o,
      wsf + G7, wsf + B7o, 512, wsf + Z2o, 256);
  final_kernel<<<2, 256, 0, stream>>>(wsf + Z2o, wsf + WL3, wsf + BL3o,
      flags, d_out);
}

// Round 3
// 2721.961 us; speedup vs baseline: 1.1543x; 1.1543x over previous
//
#include <hip/hip_runtime.h>
#include <hip/hip_bf16.h>
#include <cstdint>

// ---------------------------------------------------------------------------
// DGCNN forward on MI355X. All math in f32; inputs auto-detected bf16/f32.
// R3: fix conv1d MODE 0 stats double-count (NaN root cause in R2).
// Design: register-blocked conv2d/conv1d (4 outputs/thread), kNN via
// dist-GEMM + wave top-k, grid 2048 for occupancy.
// ---------------------------------------------------------------------------

static constexpr int BB  = 8;     // batch
static constexpr int NN  = 1024;  // points
static constexpr int KNB = 20;    // neighbors
static constexpr float BNEPS = 1e-5f;

static constexpr int NIN = 25;

__constant__ int c_cum[NIN + 1] = {
    0, 24576, 24960, 33152, 49536, 115072, 639360,
    1687936, 1819008, 1819264, 1829504, 1829544, 1829608, 1829672, 1829736,
    1829800, 1829928, 1830056, 1830312, 1830568, 1831592, 1832616, 1833128,
    1833640, 1833896, 1834152};
__constant__ int c_trO[NIN] = {0, 64, 64, 128, 256, 1024, 0, 0, 0, 0, 0,
                               0, 0, 0, 0, 0, 0, 0, 0, 0, 0, 0, 0, 0, 0};
__constant__ int c_trI[NIN] = {0, 6, 128, 128, 256, 512, 0, 0, 0, 0, 0,
                               0, 0, 0, 0, 0, 0, 0, 0, 0, 0, 0, 0, 0, 0};

enum : int {
  XIN = 0, WT1 = 24576, WT2 = 24960, WT3 = 33152, WT4 = 49536, WT5 = 115072,
  WL1 = 639360, WL2 = 1687936, BL2o = 1819008, WL3 = 1819264, BL3o = 1829504,
  G1 = 1829544, B1o = 1829608, G2 = 1829672, B2o = 1829736,
  G3 = 1829800, B3o = 1829928, G4 = 1830056, B4o = 1830312,
  G5 = 1830568, B5o = 1831592, G6 = 1832616, B6o = 1833128,
  G7 = 1833640, B7o = 1833896,
  XXo = 1834240,        // 8192 f
  IDXo = 1842432,       // 163840 i32
  HCATo = 2006272,      // 8*512*1024 f
  STATSo = 6200576,     // 5 layers * 4096 f (sum, sumsq, scale, shift)
  ZMAXo = 6221056,      // 8192 u32 (encoded max)
  ZSUMo = 6229248,      // 8192 f
  Z2048o = 6237440,     // 8*2048 f
  Z1o = 6253824,        // 8*512 f
  Z2o = 6257920,        // 8*256 f
  FLAGSo = 6259968,     // 32 i32
  DISTo = 6260736       // 8*1024*1024 f (optional fast-knn buffer)
};
static constexpr int TOTAL_IN = 1834152;
static constexpr size_t WS_NEED_FAST =
    ((size_t)DISTo + (size_t)8 * 1024 * 1024) * 4;

struct Ptrs { const void* p[NIN]; };

__device__ __forceinline__ unsigned enc_f32(float x) {
  unsigned u = __float_as_uint(x);
  return (u & 0x80000000u) ? ~u : (u | 0x80000000u);
}
__device__ __forceinline__ float dec_f32(unsigned u) {
  unsigned b = (u & 0x80000000u) ? (u & 0x7FFFFFFFu) : ~u;
  return __uint_as_float(b);
}
__device__ __forceinline__ float lrelu(float y) { return (y < 0.f) ? 0.2f * y : y; }

// ---------------------------------------------------------------------------
// dtype detection / conversion
// ---------------------------------------------------------------------------
__global__ void detect_kernel(Ptrs ptrs, int* __restrict__ flags) {
  const int i = blockIdx.x;
  const unsigned* p = (const unsigned*)ptrs.p[i];
  const int n = c_cum[i + 1] - c_cum[i];
  int words = n >> 1; if (words > 64) words = 64;
  const int t = threadIdx.x;
  unsigned w = (t < words) ? p[t] : 0u;
  bool nz = (w != 0u);
  unsigned e = (w >> 7) & 0xFFu;
  bool pl = nz && (e >= 96u) && (e <= 140u);
  unsigned long long mnz = __ballot(nz);
  unsigned long long mpl = __ballot(pl);
  if (t == 0) {
    int cnz = __popcll(mnz), cpl = __popcll(mpl);
    flags[i] = (cnz == 0) ? 2 : ((2 * cpl > words) ? 1 : 0);
  }
}

__global__ void globalflag_kernel(int* __restrict__ flags) {
  int anyf32 = 0, anybf = 0;
  for (int i = 0; i < NIN; ++i) {
    if (flags[i] == 0) anyf32 = 1;
    if (flags[i] == 1) anybf = 1;
  }
  flags[NIN] = (anybf && !anyf32) ? 1 : 0;
}

__global__ void convert_kernel(Ptrs ptrs, const int* __restrict__ flags,
                               float* __restrict__ ws) {
  const int e = blockIdx.x * 256 + threadIdx.x;
  if (e >= TOTAL_IN) return;
  int i = 0;
  while (e >= c_cum[i + 1]) ++i;
  const int el = e - c_cum[i];
  int src;
  const int O = c_trO[i];
  if (O > 0) {
    const int I = c_trI[i];
    const int o = el % O, ii = el / O;
    src = o * I + ii;
  } else src = el;
  float v;
  const int fl = flags[i];
  if (fl == 2) v = 0.f;
  else if (fl == 1) {
    const unsigned short u = ((const unsigned short*)ptrs.p[i])[src];
    v = __uint_as_float(((unsigned)u) << 16);
  } else v = ((const float*)ptrs.p[i])[src];
  ws[e] = v;
}

__global__ void zero_kernel(float* __restrict__ p, int n) {
  const int i = blockIdx.x * 256 + threadIdx.x;
  if (i < n) p[i] = 0.f;
}

// ---------------------------------------------------------------------------
// xx[b][n] = sum_c x[b][c][n]^2
// ---------------------------------------------------------------------------
__global__ void xx_kernel(const float* __restrict__ xbase, int bstr, int C,
                          float* __restrict__ xx) {
  const int i = blockIdx.x * 256 + threadIdx.x;
  if (i >= BB * NN) return;
  const int b = i >> 10, n = i & 1023;
  const float* xb = xbase + (size_t)b * bstr;
  float s = 0.f;
  for (int c = 0; c < C; ++c) { const float v = xb[c * NN + n]; s = fmaf(v, v, s); }
  xx[i] = s;
}

// ---------------------------------------------------------------------------
// dist GEMM: D[b][n][m] = 2*dot(x_n,x_m) - xx[n] - xx[m]
// grid = BB*16*16 blocks; block computes 64x64 tile, thread 4x4.
// ---------------------------------------------------------------------------
template <int C>
__global__ __launch_bounds__(256) void dist_kernel(
    const float* __restrict__ xbase, int bstr, const float* __restrict__ xx,
    float* __restrict__ D) {
  __shared__ __align__(16) float s_a[16][64];
  __shared__ __align__(16) float s_b[16][64];
  const int t = threadIdx.x;
  const int bx = blockIdx.x;
  const int b = bx >> 8;
  const int tn0 = ((bx >> 4) & 15) * 64;
  const int tm0 = (bx & 15) * 64;
  const float* xb = xbase + (size_t)b * bstr;
  const int tn = (t & 15) * 4;
  const int tm = (t >> 4) * 4;
  float acc[4][4] = {};
  for (int c0 = 0; c0 < C; c0 += 16) {
    const int kc = (C - c0 < 16) ? (C - c0) : 16;
    for (int i = t; i < 16 * 64; i += 256) {
      const int cc = i >> 6, col = i & 63;
      const bool ok = cc < kc;
      s_a[cc][col] = ok ? xb[(c0 + cc) * NN + tn0 + col] : 0.f;
      s_b[cc][col] = ok ? xb[(c0 + cc) * NN + tm0 + col] : 0.f;
    }
    __syncthreads();
#pragma unroll
    for (int cc = 0; cc < 16; ++cc) {
      const float4 av = *(const float4*)&s_a[cc][tn];
      const float4 bv = *(const float4*)&s_b[cc][tm];
      acc[0][0] = fmaf(av.x, bv.x, acc[0][0]);
      acc[0][1] = fmaf(av.x, bv.y, acc[0][1]);
      acc[0][2] = fmaf(av.x, bv.z, acc[0][2]);
      acc[0][3] = fmaf(av.x, bv.w, acc[0][3]);
      acc[1][0] = fmaf(av.y, bv.x, acc[1][0]);
      acc[1][1] = fmaf(av.y, bv.y, acc[1][1]);
      acc[1][2] = fmaf(av.y, bv.z, acc[1][2]);
      acc[1][3] = fmaf(av.y, bv.w, acc[1][3]);
      acc[2][0] = fmaf(av.z, bv.x, acc[2][0]);
      acc[2][1] = fmaf(av.z, bv.y, acc[2][1]);
      acc[2][2] = fmaf(av.z, bv.z, acc[2][2]);
      acc[2][3] = fmaf(av.z, bv.w, acc[2][3]);
      acc[3][0] = fmaf(av.w, bv.x, acc[3][0]);
      acc[3][1] = fmaf(av.w, bv.y, acc[3][1]);
      acc[3][2] = fmaf(av.w, bv.z, acc[3][2]);
      acc[3][3] = fmaf(av.w, bv.w, acc[3][3]);
    }
    __syncthreads();
  }
  const float4 xxm = *(const float4*)&xx[(b << 10) + tm0 + tm];
  float* Db = D + ((size_t)b << 20);
#pragma unroll
  for (int i = 0; i < 4; ++i) {
    const float xxn = xx[(b << 10) + tn0 + tn + i];
    float4 o;
    o.x = 2.f * acc[i][0] - xxn - xxm.x;
    o.y = 2.f * acc[i][1] - xxn - xxm.y;
    o.z = 2.f * acc[i][2] - xxn - xxm.z;
    o.w = 2.f * acc[i][3] - xxn - xxm.w;
    *(float4*)&Db[(size_t)(tn0 + tn + i) * NN + tm0 + tm] = o;
  }
}

// top-20 per row; one wave per row; tie -> lower index (matches lax.top_k)
__global__ __launch_bounds__(256) void topk_kernel(const float* __restrict__ D,
                                                   int* __restrict__ idxb) {
  const int t = threadIdx.x;
  const int lane = t & 63;
  const int row = blockIdx.x * 4 + (t >> 6);
  const float* Dr = D + ((size_t)row << 10);
  float v[16];
#pragma unroll
  for (int j = 0; j < 16; ++j) v[j] = Dr[j * 64 + lane];
  for (int kk = 0; kk < KNB; ++kk) {
    float bv = v[0]; int bj = 0;
#pragma unroll
    for (int j = 1; j < 16; ++j)
      if (v[j] > bv) { bv = v[j]; bj = j; }
    int bi = bj * 64 + lane;
    for (int off = 32; off > 0; off >>= 1) {
      const float v2 = __shfl_down(bv, off, 64);
      const int i2 = __shfl_down(bi, off, 64);
      if (v2 > bv || (v2 == bv && i2 < bi)) { bv = v2; bi = i2; }
    }
    bi = __shfl(bi, 0, 64);
    if (lane == 0) idxb[row * KNB + kk] = bi;
    if ((bi & 63) == lane) v[bi >> 6] = -3.4e38f;
  }
}

// ---------------------------------------------------------------------------
// fallback kNN (used only if ws too small for dist buffer)
// ---------------------------------------------------------------------------
template <int C>
__global__ __launch_bounds__(256) void knn_kernel(const float* __restrict__ xbase,
                                                  int bstr,
                                                  const float* __restrict__ xx,
                                                  int* __restrict__ idxb) {
  __shared__ __align__(16) float s_d[NN];
  __shared__ float s_ctr[C];
  __shared__ float s_rv[4];
  __shared__ int s_ri[4];
  const int t = threadIdx.x;
  const int p = blockIdx.x;
  const int b = p >> 10, n = p & 1023;
  const float* xb = xbase + (size_t)b * bstr;
  if (t < C) s_ctr[t] = xb[t * NN + n];
  __syncthreads();
  {
    const int m0 = t * 4;
    float4 dot = make_float4(0.f, 0.f, 0.f, 0.f);
    for (int c = 0; c < C; ++c) {
      const float4 xv = *(const float4*)&xb[c * NN + m0];
      const float cv = s_ctr[c];
      dot.x = fmaf(cv, xv.x, dot.x);
      dot.y = fmaf(cv, xv.y, dot.y);
      dot.z = fmaf(cv, xv.z, dot.z);
      dot.w = fmaf(cv, xv.w, dot.w);
    }
    const float xxn = xx[p];
    const float4 xxm = *(const float4*)&xx[(b << 10) + m0];
    float4 dd;
    dd.x = 2.f * dot.x - xxn - xxm.x;
    dd.y = 2.f * dot.y - xxn - xxm.y;
    dd.z = 2.f * dot.z - xxn - xxm.z;
    dd.w = 2.f * dot.w - xxn - xxm.w;
    *(float4*)&s_d[m0] = dd;
  }
  __syncthreads();
  for (int kk = 0; kk < KNB; ++kk) {
    const int m0 = t * 4;
    const float4 dv = *(const float4*)&s_d[m0];
    float bv = dv.x; int bi = m0;
    if (dv.y > bv) { bv = dv.y; bi = m0 + 1; }
    if (dv.z > bv) { bv = dv.z; bi = m0 + 2; }
    if (dv.w > bv) { bv = dv.w; bi = m0 + 3; }
    for (int off = 32; off > 0; off >>= 1) {
      const float v2 = __shfl_down(bv, off, 64);
      const int i2 = __shfl_down(bi, off, 64);
      if (v2 > bv || (v2 == bv && i2 < bi)) { bv = v2; bi = i2; }
    }
    if ((t & 63) == 0) { s_rv[t >> 6] = bv; s_ri[t >> 6] = bi; }
    __syncthreads();
    if (t == 0) {
      float v = s_rv[0]; int i0 = s_ri[0];
      for (int w = 1; w < 4; ++w)
        if (s_rv[w] > v || (s_rv[w] == v && s_ri[w] < i0)) { v = s_rv[w]; i0 = s_ri[w]; }
      idxb[p * KNB + kk] = i0;
      s_d[i0] = -3.4e38f;
    }
    __syncthreads();
  }
}

// ---------------------------------------------------------------------------
// edge-conv, stage-1 variant (C=3).
// ---------------------------------------------------------------------------
template <int C, int COUT, int MODE>
__global__ __launch_bounds__(256) void conv2d_kernel(
    const float* __restrict__ xbase, int bstr, const int* __restrict__ idxb,
    const float* __restrict__ WT, float* __restrict__ stats,
    float* __restrict__ hout) {
  constexpr int G = 256 / COUT;
  constexpr int NPER = KNB / G;
  __shared__ __align__(16) float s_nbm[KNB * C];
  __shared__ float s_ctr[C];
  __shared__ float s_wc[COUT];
  __shared__ int s_idx[KNB];
  __shared__ float s_red[256];
  const int t = threadIdx.x;
  const int o = t % COUT, rep = t / COUT;
  float sc = 0.f, sh = 0.f;
  if (MODE == 1) { sc = stats[2048 + o]; sh = stats[3072 + o]; }
  float s1 = 0.f, s2 = 0.f;
  for (int p = blockIdx.x; p < BB * NN; p += gridDim.x) {
    const int b = p >> 10, n = p & 1023;
    const float* xb = xbase + (size_t)b * bstr;
    if (t < C) s_ctr[t] = xb[t * NN + n];
    if (t >= 224 && t < 224 + KNB) s_idx[t - 224] = idxb[p * KNB + (t - 224)];
    __syncthreads();
    for (int i = t; i < KNB * C; i += 256) {
      const int kk = i / C, c = i - kk * C;
      s_nbm[i] = xb[c * NN + s_idx[kk]] - s_ctr[c];
    }
    if (t < COUT) {
      float s = 0.f;
      for (int c = 0; c < C; ++c) s = fmaf(WT[(C + c) * COUT + t], s_ctr[c], s);
      s_wc[t] = s;
    }
    __syncthreads();
    float acc[NPER];
#pragma unroll
    for (int j = 0; j < NPER; ++j) acc[j] = 0.f;
    for (int c = 0; c < C; ++c) {
      const float w = WT[c * COUT + o];
#pragma unroll
      for (int j = 0; j < NPER; ++j)
        acc[j] = fmaf(w, s_nbm[(rep + j * G) * C + c], acc[j]);
    }
    const float wc = s_wc[o];
    if (MODE == 0) {
#pragma unroll
      for (int j = 0; j < NPER; ++j) {
        const float y = acc[j] + wc;
        s1 += y; s2 = fmaf(y, y, s2);
      }
      __syncthreads();
    } else {
      float mx = -3.4e38f;
#pragma unroll
      for (int j = 0; j < NPER; ++j) {
        const float y = lrelu(fmaf(sc, acc[j] + wc, sh));
        mx = fmaxf(mx, y);
      }
      s_red[t] = mx;
      __syncthreads();
      if (t < COUT) {
        float m = s_red[t];
        for (int r = 1; r < G; ++r) m = fmaxf(m, s_red[t + r * COUT]);
        hout[(size_t)b * (512 * 1024) + t * NN + n] = m;
      }
      __syncthreads();
    }
  }
  if (MODE == 0) {
    s_red[t] = s1; __syncthreads();
    if (t < COUT) {
      float s = s_red[t];
      for (int r = 1; r < G; ++r) s += s_red[t + r * COUT];
      atomicAdd(&stats[t], s);
    }
    __syncthreads();
    s_red[t] = s2; __syncthreads();
    if (t < COUT) {
      float s = s_red[t];
      for (int r = 1; r < G; ++r) s += s_red[t + r * COUT];
      atomicAdd(&stats[1024 + t], s);
    }
  }
}

// ---------------------------------------------------------------------------
// edge-conv, register-blocked: thread = 4 outputs x k-subset.
// ---------------------------------------------------------------------------
template <int C, int COUT, int MODE>
__global__ __launch_bounds__(256) void conv2d_big_kernel(
    const float* __restrict__ xbase, int bstr, const int* __restrict__ idxb,
    const float* __restrict__ WT, float* __restrict__ stats,
    float* __restrict__ hout) {
  constexpr int OQ = COUT / 4;
  constexpr int R = 256 / OQ;
  constexpr int NP = (KNB + R - 1) / R;
  __shared__ __align__(16) float s_nbm[KNB * C];
  __shared__ float s_ctr[C];
  __shared__ __align__(16) float s_wc[COUT];
  __shared__ int s_idx[KNB];
  __shared__ __align__(16) float s_red[1024];   // R * COUT == 1024
  const int t = threadIdx.x;
  const int oq = t & (OQ - 1);
  const int rep = t / OQ;
  const int o0 = oq * 4;
  float sca[4], sha[4];
  if (MODE == 1) {
    const float4 s4 = *(const float4*)&stats[2048 + o0];
    const float4 h4 = *(const float4*)&stats[3072 + o0];
    sca[0] = s4.x; sca[1] = s4.y; sca[2] = s4.z; sca[3] = s4.w;
    sha[0] = h4.x; sha[1] = h4.y; sha[2] = h4.z; sha[3] = h4.w;
  }
  float s1[4] = {}, s2[4] = {};
  for (int p = blockIdx.x; p < BB * NN; p += gridDim.x) {
    const int b = p >> 10, n = p & 1023;
    const float* xb = xbase + (size_t)b * bstr;
    if (t < C) s_ctr[t] = xb[t * NN + n];
    if (t >= 224 && t < 224 + KNB) s_idx[t - 224] = idxb[p * KNB + (t - 224)];
    __syncthreads();
    for (int i = t; i < KNB * C; i += 256) {
      const int kk = i / C, c = i - kk * C;
      s_nbm[i] = xb[c * NN + s_idx[kk]] - s_ctr[c];
    }
    if (t < COUT) {
      float s = 0.f;
      for (int c = 0; c < C; ++c) s = fmaf(WT[(C + c) * COUT + t], s_ctr[c], s);
      s_wc[t] = s;
    }
    __syncthreads();
    float acc[NP][4];
#pragma unroll
    for (int j = 0; j < NP; ++j)
#pragma unroll
      for (int q = 0; q < 4; ++q) acc[j][q] = 0.f;
    for (int c = 0; c < C; c += 4) {
      const float4 w0 = *(const float4*)&WT[(c + 0) * COUT + o0];
      const float4 w1 = *(const float4*)&WT[(c + 1) * COUT + o0];
      const float4 w2 = *(const float4*)&WT[(c + 2) * COUT + o0];
      const float4 w3 = *(const float4*)&WT[(c + 3) * COUT + o0];
#pragma unroll
      for (int j = 0; j < NP; ++j) {
        const int kk = rep + j * R;
        if (NP * R == KNB || kk < KNB) {
          const float4 f = *(const float4*)&s_nbm[kk * C + c];
          acc[j][0] = fmaf(w0.x, f.x, acc[j][0]);
          acc[j][0] = fmaf(w1.x, f.y, acc[j][0]);
          acc[j][0] = fmaf(w2.x, f.z, acc[j][0]);
          acc[j][0] = fmaf(w3.x, f.w, acc[j][0]);
          acc[j][1] = fmaf(w0.y, f.x, acc[j][1]);
          acc[j][1] = fmaf(w1.y, f.y, acc[j][1]);
          acc[j][1] = fmaf(w2.y, f.z, acc[j][1]);
          acc[j][1] = fmaf(w3.y, f.w, acc[j][1]);
          acc[j][2] = fmaf(w0.z, f.x, acc[j][2]);
          acc[j][2] = fmaf(w1.z, f.y, acc[j][2]);
          acc[j][2] = fmaf(w2.z, f.z, acc[j][2]);
          acc[j][2] = fmaf(w3.z, f.w, acc[j][2]);
          acc[j][3] = fmaf(w0.w, f.x, acc[j][3]);
          acc[j][3] = fmaf(w1.w, f.y, acc[j][3]);
          acc[j][3] = fmaf(w2.w, f.z, acc[j][3]);
          acc[j][3] = fmaf(w3.w, f.w, acc[j][3]);
        }
      }
    }
    const float4 wc4 = *(const float4*)&s_wc[o0];
    const float wca[4] = {wc4.x, wc4.y, wc4.z, wc4.w};
    if (MODE == 0) {
#pragma unroll
      for (int j = 0; j < NP; ++j) {
        if (NP * R == KNB || rep + j * R < KNB) {
#pragma unroll
          for (int q = 0; q < 4; ++q) {
            const float y = acc[j][q] + wca[q];
            s1[q] += y; s2[q] = fmaf(y, y, s2[q]);
          }
        }
      }
      __syncthreads();
    } else {
      float mx[4] = {-3.4e38f, -3.4e38f, -3.4e38f, -3.4e38f};
#pragma unroll
      for (int j = 0; j < NP; ++j) {
        if (NP * R == KNB || rep + j * R < KNB) {
#pragma unroll
          for (int q = 0; q < 4; ++q) {
            const float y = lrelu(fmaf(sca[q], acc[j][q] + wca[q], sha[q]));
            mx[q] = fmaxf(mx[q], y);
          }
        }
      }
      *(float4*)&s_red[rep * COUT + o0] = make_float4(mx[0], mx[1], mx[2], mx[3]);
      __syncthreads();
      if (t < COUT) {
        float m = s_red[t];
#pragma unroll
        for (int r = 1; r < R; ++r) m = fmaxf(m, s_red[r * COUT + t]);
        hout[(size_t)b * (512 * 1024) + t * NN + n] = m;
      }
      __syncthreads();
    }
  }
  if (MODE == 0) {
    *(float4*)&s_red[rep * COUT + o0] = make_float4(s1[0], s1[1], s1[2], s1[3]);
    __syncthreads();
    if (t < COUT) {
      float s = s_red[t];
#pragma unroll
      for (int r = 1; r < R; ++r) s += s_red[r * COUT + t];
      atomicAdd(&stats[t], s);
    }
    __syncthreads();
    *(float4*)&s_red[rep * COUT + o0] = make_float4(s2[0], s2[1], s2[2], s2[3]);
    __syncthreads();
    if (t < COUT) {
      float s = s_red[t];
#pragma unroll
      for (int r = 1; r < R; ++r) s += s_red[r * COUT + t];
      atomicAdd(&stats[1024 + t], s);
    }
  }
}

// ---------------------------------------------------------------------------
// finalize BN
// ---------------------------------------------------------------------------
__global__ void bn_finalize_kernel(float* __restrict__ stats,
                                   const float* __restrict__ g,
                                   const float* __restrict__ bb, int cout,
                                   float inv_cnt) {
  const int o = blockIdx.x * 256 + threadIdx.x;
  if (o >= cout) return;
  const float mean = stats[o] * inv_cnt;
  const float var = stats[1024 + o] * inv_cnt - mean * mean;
  const float s = g[o] * rsqrtf(var + BNEPS);
  stats[2048 + o] = s;
  stats[3072 + o] = bb[o] - mean * s;
}

// ---------------------------------------------------------------------------
// conv1d 512->1024, register-blocked: thread = 4 outputs x 8 n.
// grid 1024 = ot(4) x b(8) x nt(32).
// ---------------------------------------------------------------------------
template <int MODE>
__global__ __launch_bounds__(256) void conv1d_kernel(
    const float* __restrict__ hcat, const float* __restrict__ WT5,
    float* __restrict__ stats, unsigned* __restrict__ zmax,
    float* __restrict__ zsum) {
  __shared__ __align__(16) float s_h[64 * 32];
  __shared__ __align__(16) float s_red[1024];
  const int t = threadIdx.x;
  const int bx = blockIdx.x;
  const int ot = bx & 3;
  const int b = (bx >> 2) & 7;
  const int nt = bx >> 5;
  const int n0 = nt * 32;
  const int oq = t & 63;
  const int rep = t >> 6;               // n-subtile of 8
  const int o0 = ot * 256 + oq * 4;
  const float* hb = hcat + (size_t)b * (512 * 1024);
  float acc[8][4] = {};
  for (int cc = 0; cc < 512; cc += 64) {
    for (int i = t; i < 64 * 32; i += 256) {
      const int c = i >> 5, nn2 = i & 31;
      s_h[i] = hb[(cc + c) * NN + n0 + nn2];
    }
    __syncthreads();
    for (int c = 0; c < 64; ++c) {
      const float4 w = *(const float4*)&WT5[(cc + c) * 1024 + o0];
      const float4 h0 = *(const float4*)&s_h[c * 32 + rep * 8];
      const float4 h1 = *(const float4*)&s_h[c * 32 + rep * 8 + 4];
      const float hv[8] = {h0.x, h0.y, h0.z, h0.w, h1.x, h1.y, h1.z, h1.w};
#pragma unroll
      for (int j = 0; j < 8; ++j) {
        acc[j][0] = fmaf(w.x, hv[j], acc[j][0]);
        acc[j][1] = fmaf(w.y, hv[j], acc[j][1]);
        acc[j][2] = fmaf(w.z, hv[j], acc[j][2]);
        acc[j][3] = fmaf(w.w, hv[j], acc[j][3]);
      }
    }
    __syncthreads();
  }
  if (MODE == 0) {
    // single clean staged reduction: sum, then sumsq (R2 bug: an extra
    // atomicAdd block here inflated sums 1.25x -> negative var -> NaN)
    float s1[4] = {}, s2[4] = {};
#pragma unroll
    for (int j = 0; j < 8; ++j)
#pragma unroll
      for (int q = 0; q < 4; ++q) {
        s1[q] += acc[j][q];
        s2[q] = fmaf(acc[j][q], acc[j][q], s2[q]);
      }
    *(float4*)&s_red[rep * 256 + oq * 4] = make_float4(s1[0], s1[1], s1[2], s1[3]);
    __syncthreads();
    {
      const float s = s_red[t] + s_red[256 + t] + s_red[512 + t] + s_red[768 + t];
      atomicAdd(&stats[ot * 256 + t], s);
    }
    __syncthreads();
    *(float4*)&s_red[rep * 256 + oq * 4] = make_float4(s2[0], s2[1], s2[2], s2[3]);
    __syncthreads();
    {
      const float s = s_red[t] + s_red[256 + t] + s_red[512 + t] + s_red[768 + t];
      atomicAdd(&stats[1024 + ot * 256 + t], s);
    }
  } else {
    const float4 s4 = *(const float4*)&stats[2048 + o0];
    const float4 h4 = *(const float4*)&stats[3072 + o0];
    const float sca[4] = {s4.x, s4.y, s4.z, s4.w};
    const float sha[4] = {h4.x, h4.y, h4.z, h4.w};
    float mx[4] = {-3.4e38f, -3.4e38f, -3.4e38f, -3.4e38f};
    float sm[4] = {};
#pragma unroll
    for (int j = 0; j < 8; ++j)
#pragma unroll
      for (int q = 0; q < 4; ++q) {
        const float y = lrelu(fmaf(sca[q], acc[j][q], sha[q]));
        mx[q] = fmaxf(mx[q], y);
        sm[q] += y;
      }
    *(float4*)&s_red[rep * 256 + oq * 4] = make_float4(mx[0], mx[1], mx[2], mx[3]);
    __syncthreads();
    {
      float m = s_red[t];
      m = fmaxf(m, s_red[256 + t]);
      m = fmaxf(m, s_red[512 + t]);
      m = fmaxf(m, s_red[768 + t]);
      atomicMax(&zmax[(b << 10) + ot * 256 + t], enc_f32(m));
    }
    __syncthreads();
    *(float4*)&s_red[rep * 256 + oq * 4] = make_float4(sm[0], sm[1], sm[2], sm[3]);
    __syncthreads();
    {
      const float s = s_red[t] + s_red[256 + t] + s_red[512 + t] + s_red[768 + t];
      atomicAdd(&zsum[(b << 10) + ot * 256 + t], s);
    }
  }
}

__global__ void zfin_kernel(const unsigned* __restrict__ zmax,
                            const float* __restrict__ zsum,
                            float* __restrict__ z) {
  const int i = blockIdx.x * 256 + threadIdx.x;
  if (i >= BB * 1024) return;
  const int b = i >> 10, o = i & 1023;
  z[b * 2048 + o] = dec_f32(zmax[i]);
  z[b * 2048 + 1024 + o] = zsum[i] * (1.f / 1024.f);
}

// ---------------------------------------------------------------------------
// MLP layer with batch-of-8 BN + lrelu fused.
// ---------------------------------------------------------------------------
__global__ __launch_bounds__(256) void mlp_kernel(
    const float* __restrict__ zin, const float* __restrict__ W,
    const float* __restrict__ bias, const float* __restrict__ g,
    const float* __restrict__ bb, int kin, float* __restrict__ out, int O) {
  __shared__ float s_red[256];
  __shared__ float s_y[8];
  const int t = threadIdx.x;
  const int o = blockIdx.x;
  float acc[8];
#pragma unroll
  for (int b = 0; b < 8; ++b) acc[b] = 0.f;
  for (int c = t; c < kin; c += 256) {
    const float w = W[(size_t)o * kin + c];
#pragma unroll
    for (int b = 0; b < 8; ++b) acc[b] = fmaf(w, zin[b * kin + c], acc[b]);
  }
  for (int b = 0; b < 8; ++b) {
    s_red[t] = acc[b];
    __syncthreads();
    for (int s = 128; s > 0; s >>= 1) {
      if (t < s) s_red[t] += s_red[t + s];
      __syncthreads();
    }
    if (t == 0) s_y[b] = s_red[0] + (bias ? bias[o] : 0.f);
    __syncthreads();
  }
  if (t == 0) {
    float m = 0.f;
    for (int b = 0; b < 8; ++b) m += s_y[b];
    m *= 0.125f;
    float v = 0.f;
    for (int b = 0; b < 8; ++b) { const float d = s_y[b] - m; v = fmaf(d, d, v); }
    v *= 0.125f;
    const float s = g[o] * rsqrtf(v + BNEPS);
    const float sh = bb[o] - m * s;
    for (int b = 0; b < 8; ++b) out[b * O + o] = lrelu(fmaf(s, s_y[b], sh));
  }
}

__global__ void final_kernel(const float* __restrict__ z2,
                             const float* __restrict__ Wl3,
                             const float* __restrict__ bl3,
                             const int* __restrict__ flags, void* out) {
  const int j = blockIdx.x * 256 + threadIdx.x;
  if (j >= 320) return;
  const int b = j / 40, o = j - b * 40;
  float s = bl3[o];
  for (int c = 0; c < 256; ++c) s = fmaf(z2[b * 256 + c], Wl3[o * 256 + c], s);
  if (flags[NIN] == 1) ((__hip_bfloat16*)out)[j] = __float2bfloat16(s);
  else ((float*)out)[j] = s;
}

// ---------------------------------------------------------------------------
extern "C" void kernel_launch(void* const* d_in, const int* in_sizes, int n_in,
                              void* d_out, int out_size, void* d_ws,
                              size_t ws_size, hipStream_t stream) {
  (void)in_sizes; (void)n_in; (void)out_size;
  float* wsf = reinterpret_cast<float*>(d_ws);
  int* flags = reinterpret_cast<int*>(wsf + FLAGSo);
  int* idxb = reinterpret_cast<int*>(wsf + IDXo);
  float* xx = wsf + XXo;
  float* hcat = wsf + HCATo;
  unsigned* zmax = reinterpret_cast<unsigned*>(wsf + ZMAXo);
  float* zsum = wsf + ZSUMo;
  float* dist = wsf + DISTo;
  const bool fastknn = ws_size >= WS_NEED_FAST;

  Ptrs ptrs;
  for (int i = 0; i < NIN; ++i) ptrs.p[i] = d_in[i];

  detect_kernel<<<NIN, 64, 0, stream>>>(ptrs, flags);
  globalflag_kernel<<<1, 1, 0, stream>>>(flags);
  convert_kernel<<<(TOTAL_IN + 255) / 256, 256, 0, stream>>>(ptrs, flags, wsf);
  zero_kernel<<<144, 256, 0, stream>>>(wsf + STATSo, 36864);

  const float inv2d = 1.f / (8.f * 1024.f * 20.f);

  // ---- stage 1 (input x, C=3) ----
  xx_kernel<<<32, 256, 0, stream>>>(wsf + XIN, 3 * NN, 3, xx);
  if (fastknn) {
    dist_kernel<3><<<2048, 256, 0, stream>>>(wsf + XIN, 3 * NN, xx, dist);
    topk_kernel<<<2048, 256, 0, stream>>>(dist, idxb);
  } else {
    knn_kernel<3><<<BB * NN, 256, 0, stream>>>(wsf + XIN, 3 * NN, xx, idxb);
  }
  conv2d_kernel<3, 64, 0><<<2048, 256, 0, stream>>>(wsf + XIN, 3 * NN, idxb,
      wsf + WT1, wsf + STATSo + 0 * 4096, hcat);
  bn_finalize_kernel<<<4, 256, 0, stream>>>(wsf + STATSo + 0 * 4096,
      wsf + G1, wsf + B1o, 64, inv2d);
  conv2d_kernel<3, 64, 1><<<2048, 256, 0, stream>>>(wsf + XIN, 3 * NN, idxb,
      wsf + WT1, wsf + STATSo + 0 * 4096, hcat + 0 * NN);

  // ---- stage 2 (x1 = hcat ch 0..63) ----
  xx_kernel<<<32, 256, 0, stream>>>(hcat, 512 * NN, 64, xx);
  if (fastknn) {
    dist_kernel<64><<<2048, 256, 0, stream>>>(hcat, 512 * NN, xx, dist);
    topk_kernel<<<2048, 256, 0, stream>>>(dist, idxb);
  } else {
    knn_kernel<64><<<BB * NN, 256, 0, stream>>>(hcat, 512 * NN, xx, idxb);
  }
  conv2d_big_kernel<64, 64, 0><<<2048, 256, 0, stream>>>(hcat, 512 * NN, idxb,
      wsf + WT2, wsf + STATSo + 1 * 4096, hcat);
  bn_finalize_kernel<<<4, 256, 0, stream>>>(wsf + STATSo + 1 * 4096,
      wsf + G2, wsf + B2o, 64, inv2d);
  conv2d_big_kernel<64, 64, 1><<<2048, 256, 0, stream>>>(hcat, 512 * NN, idxb,
      wsf + WT2, wsf + STATSo + 1 * 4096, hcat + 64 * NN);

  // ---- stage 3 (x2 = hcat ch 64..127) ----
  xx_kernel<<<32, 256, 0, stream>>>(hcat + 64 * NN, 512 * NN, 64, xx);
  if (fastknn) {
    dist_kernel<64><<<2048, 256, 0, stream>>>(hcat + 64 * NN, 512 * NN, xx, dist);
    topk_kernel<<<2048, 256, 0, stream>>>(dist, idxb);
  } else {
    knn_kernel<64><<<BB * NN, 256, 0, stream>>>(hcat + 64 * NN, 512 * NN, xx, idxb);
  }
  conv2d_big_kernel<64, 128, 0><<<2048, 256, 0, stream>>>(hcat + 64 * NN,
      512 * NN, idxb, wsf + WT3, wsf + STATSo + 2 * 4096, hcat);
  bn_finalize_kernel<<<4, 256, 0, stream>>>(wsf + STATSo + 2 * 4096,
      wsf + G3, wsf + B3o, 128, inv2d);
  conv2d_big_kernel<64, 128, 1><<<2048, 256, 0, stream>>>(hcat + 64 * NN,
      512 * NN, idxb, wsf + WT3, wsf + STATSo + 2 * 4096, hcat + 128 * NN);

  // ---- stage 4 (x3 = hcat ch 128..255, C=128) ----
  xx_kernel<<<32, 256, 0, stream>>>(hcat + 128 * NN, 512 * NN, 128, xx);
  if (fastknn) {
    dist_kernel<128><<<2048, 256, 0, stream>>>(hcat + 128 * NN, 512 * NN, xx, dist);
    topk_kernel<<<2048, 256, 0, stream>>>(dist, idxb);
  } else {
    knn_kernel<128><<<BB * NN, 256, 0, stream>>>(hcat + 128 * NN, 512 * NN, xx, idxb);
  }
  conv2d_big_kernel<128, 256, 0><<<2048, 256, 0, stream>>>(hcat + 128 * NN,
      512 * NN, idxb, wsf + WT4, wsf + STATSo + 3 * 4096, hcat);
  bn_finalize_kernel<<<4, 256, 0, stream>>>(wsf + STATSo + 3 * 4096,
      wsf + G4, wsf + B4o, 256, inv2d);
  conv2d_big_kernel<128, 256, 1><<<2048, 256, 0, stream>>>(hcat + 128 * NN,
      512 * NN, idxb, wsf + WT4, wsf + STATSo + 3 * 4096, hcat + 256 * NN);

  // ---- conv1d 512->1024 + pooling ----
  conv1d_kernel<0><<<1024, 256, 0, stream>>>(hcat, wsf + WT5,
      wsf + STATSo + 4 * 4096, zmax, zsum);
  bn_finalize_kernel<<<4, 256, 0, stream>>>(wsf + STATSo + 4 * 4096,
      wsf + G5, wsf + B5o, 1024, 1.f / 8192.f);
  conv1d_kernel<1><<<1024, 256, 0, stream>>>(hcat, wsf + WT5,
      wsf + STATSo + 4 * 4096, zmax, zsum);
  zfin_kernel<<<32, 256, 0, stream>>>(zmax, zsum, wsf + Z2048o);

  // ---- MLP head ----
  mlp_kernel<<<512, 256, 0, stream>>>(wsf + Z2048o, wsf + WL1, nullptr,
      wsf + G6, wsf + B6o, 2048, wsf + Z1o, 512);
  mlp_kernel<<<256, 256, 0, stream>>>(wsf + Z1o, wsf + WL2, wsf + BL2o,
      wsf + G7, wsf + B7o, 512, wsf + Z2o, 256);
  final_kernel<<<2, 256, 0, stream>>>(wsf + Z2o, wsf + WL3, wsf + BL3o,
      flags, d_out);
}

// Round 4
// 778.134 us; speedup vs baseline: 4.0380x; 3.4981x over previous
//
#include <hip/hip_runtime.h>
#include <hip/hip_bf16.h>
#include <cstdint>

// ---------------------------------------------------------------------------
// DGCNN forward on MI355X. All math f32; inputs auto-detected bf16/f32.
// R4: edge-conv restructured as GEMM (U/Vd) + coalesced post-gather with
// fused stats+min/max; conv1d as GEMM + fused stats + cheap pool pass.
// ---------------------------------------------------------------------------

static constexpr int BB  = 8;
static constexpr int NN  = 1024;
static constexpr int KNB = 20;
static constexpr float BNEPS = 1e-5f;

static constexpr int NIN = 25;

__constant__ int c_cum[NIN + 1] = {
    0, 24576, 24960, 33152, 49536, 115072, 639360,
    1687936, 1819008, 1819264, 1829504, 1829544, 1829608, 1829672, 1829736,
    1829800, 1829928, 1830056, 1830312, 1830568, 1831592, 1832616, 1833128,
    1833640, 1833896, 1834152};
__constant__ int c_trO[NIN] = {0, 64, 64, 128, 256, 1024, 0, 0, 0, 0, 0,
                               0, 0, 0, 0, 0, 0, 0, 0, 0, 0, 0, 0, 0, 0};
__constant__ int c_trI[NIN] = {0, 6, 128, 128, 256, 512, 0, 0, 0, 0, 0,
                               0, 0, 0, 0, 0, 0, 0, 0, 0, 0, 0, 0, 0, 0};

enum : int {
  XIN = 0, WT1 = 24576, WT2 = 24960, WT3 = 33152, WT4 = 49536, WT5 = 115072,
  WL1 = 639360, WL2 = 1687936, BL2o = 1819008, WL3 = 1819264, BL3o = 1829504,
  G1 = 1829544, B1o = 1829608, G2 = 1829672, B2o = 1829736,
  G3 = 1829800, B3o = 1829928, G4 = 1830056, B4o = 1830312,
  G5 = 1830568, B5o = 1831592, G6 = 1832616, B6o = 1833128,
  G7 = 1833640, B7o = 1833896,
  XXo = 1834240,        // 8192 f
  IDXo = 1842432,       // 163840 i32
  HCATo = 2006272,      // 8*512*1024 f
  STATSo = 6200576,     // 5 layers * 4096 f (sum, sumsq, scale, shift)
  Z2048o = 6237440,     // 8*2048 f
  Z1o = 6253824,        // 8*512 f
  Z2o = 6257920,        // 8*256 f
  FLAGSo = 6259968,     // 32 i32
  DISTo = 6260736       // 8M floats window: dist / {U,Vd,ymax,ymin} / Y5
};
static constexpr int TOTAL_IN = 1834152;
// aliases inside the 8M-float window (each 2M floats = max 8*1024*256)
enum : int {
  UOFF  = DISTo + 0,
  VDOFF = DISTo + 2097152,
  YMXo  = DISTo + 4194304,
  YMNo  = DISTo + 6291456,
  Y5o   = DISTo + 0            // conv1d phase reuses whole window
};

struct Ptrs { const void* p[NIN]; };

__device__ __forceinline__ float lrelu(float y) { return (y < 0.f) ? 0.2f * y : y; }

// ---------------------------------------------------------------------------
// dtype detection / conversion
// ---------------------------------------------------------------------------
__global__ void detect_kernel(Ptrs ptrs, int* __restrict__ flags) {
  const int i = blockIdx.x;
  const unsigned* p = (const unsigned*)ptrs.p[i];
  const int n = c_cum[i + 1] - c_cum[i];
  int words = n >> 1; if (words > 64) words = 64;
  const int t = threadIdx.x;
  unsigned w = (t < words) ? p[t] : 0u;
  bool nz = (w != 0u);
  unsigned e = (w >> 7) & 0xFFu;
  bool pl = nz && (e >= 96u) && (e <= 140u);
  unsigned long long mnz = __ballot(nz);
  unsigned long long mpl = __ballot(pl);
  if (t == 0) {
    int cnz = __popcll(mnz), cpl = __popcll(mpl);
    flags[i] = (cnz == 0) ? 2 : ((2 * cpl > words) ? 1 : 0);
  }
}

__global__ void globalflag_kernel(int* __restrict__ flags) {
  int anyf32 = 0, anybf = 0;
  for (int i = 0; i < NIN; ++i) {
    if (flags[i] == 0) anyf32 = 1;
    if (flags[i] == 1) anybf = 1;
  }
  flags[NIN] = (anybf && !anyf32) ? 1 : 0;
}

__global__ void convert_kernel(Ptrs ptrs, const int* __restrict__ flags,
                               float* __restrict__ ws) {
  const int e = blockIdx.x * 256 + threadIdx.x;
  if (e >= TOTAL_IN) return;
  int i = 0;
  while (e >= c_cum[i + 1]) ++i;
  const int el = e - c_cum[i];
  int src;
  const int O = c_trO[i];
  if (O > 0) {
    const int I = c_trI[i];
    const int o = el % O, ii = el / O;
    src = o * I + ii;
  } else src = el;
  float v;
  const int fl = flags[i];
  if (fl == 2) v = 0.f;
  else if (fl == 1) {
    const unsigned short u = ((const unsigned short*)ptrs.p[i])[src];
    v = __uint_as_float(((unsigned)u) << 16);
  } else v = ((const float*)ptrs.p[i])[src];
  ws[e] = v;
}

__global__ void zero_kernel(float* __restrict__ p, int n) {
  const int i = blockIdx.x * 256 + threadIdx.x;
  if (i < n) p[i] = 0.f;
}

// ---------------------------------------------------------------------------
// xx[b][n] = sum_c x[b][c][n]^2
// ---------------------------------------------------------------------------
__global__ void xx_kernel(const float* __restrict__ xbase, int bstr, int C,
                          float* __restrict__ xx) {
  const int i = blockIdx.x * 256 + threadIdx.x;
  if (i >= BB * NN) return;
  const int b = i >> 10, n = i & 1023;
  const float* xb = xbase + (size_t)b * bstr;
  float s = 0.f;
  for (int c = 0; c < C; ++c) { const float v = xb[c * NN + n]; s = fmaf(v, v, s); }
  xx[i] = s;
}

// ---------------------------------------------------------------------------
// dist GEMM: D[b][n][m] = 2*dot - xx[n] - xx[m]; 64x64 tile, thread 4x4
// ---------------------------------------------------------------------------
template <int C>
__global__ __launch_bounds__(256) void dist_kernel(
    const float* __restrict__ xbase, int bstr, const float* __restrict__ xx,
    float* __restrict__ D) {
  __shared__ __align__(16) float s_a[16][64];
  __shared__ __align__(16) float s_b[16][64];
  const int t = threadIdx.x;
  const int bx = blockIdx.x;
  const int b = bx >> 8;
  const int tn0 = ((bx >> 4) & 15) * 64;
  const int tm0 = (bx & 15) * 64;
  const float* xb = xbase + (size_t)b * bstr;
  const int tn = (t >> 4) * 4;
  const int tm = (t & 15) * 4;
  float acc[4][4] = {};
  for (int c0 = 0; c0 < C; c0 += 16) {
    const int kc = (C - c0 < 16) ? (C - c0) : 16;
    for (int i = t; i < 16 * 64; i += 256) {
      const int cc = i >> 6, col = i & 63;
      const bool ok = cc < kc;
      s_a[cc][col] = ok ? xb[(c0 + cc) * NN + tn0 + col] : 0.f;
      s_b[cc][col] = ok ? xb[(c0 + cc) * NN + tm0 + col] : 0.f;
    }
    __syncthreads();
#pragma unroll
    for (int cc = 0; cc < 16; ++cc) {
      const float4 av = *(const float4*)&s_a[cc][tn];
      const float4 bv = *(const float4*)&s_b[cc][tm];
      const float aa[4] = {av.x, av.y, av.z, av.w};
      const float bb2[4] = {bv.x, bv.y, bv.z, bv.w};
#pragma unroll
      for (int i = 0; i < 4; ++i)
#pragma unroll
        for (int j = 0; j < 4; ++j) acc[i][j] = fmaf(aa[i], bb2[j], acc[i][j]);
    }
    __syncthreads();
  }
  const float4 xxm = *(const float4*)&xx[(b << 10) + tm0 + tm];
  const float xb4[4] = {xxm.x, xxm.y, xxm.z, xxm.w};
  float* Db = D + ((size_t)b << 20);
#pragma unroll
  for (int i = 0; i < 4; ++i) {
    const float xxn = xx[(b << 10) + tn0 + tn + i];
    float4 o;
    o.x = 2.f * acc[i][0] - xxn - xb4[0];
    o.y = 2.f * acc[i][1] - xxn - xb4[1];
    o.z = 2.f * acc[i][2] - xxn - xb4[2];
    o.w = 2.f * acc[i][3] - xxn - xb4[3];
    *(float4*)&Db[(size_t)(tn0 + tn + i) * NN + tm0 + tm] = o;
  }
}

// top-20 per row; one wave per row; tie -> lower index (matches lax.top_k)
__global__ __launch_bounds__(256) void topk_kernel(const float* __restrict__ D,
                                                   int* __restrict__ idxb) {
  const int t = threadIdx.x;
  const int lane = t & 63;
  const int row = blockIdx.x * 4 + (t >> 6);
  const float* Dr = D + ((size_t)row << 10);
  float v[16];
#pragma unroll
  for (int j = 0; j < 16; ++j) v[j] = Dr[j * 64 + lane];
  for (int kk = 0; kk < KNB; ++kk) {
    float bv = v[0]; int bj = 0;
#pragma unroll
    for (int j = 1; j < 16; ++j)
      if (v[j] > bv) { bv = v[j]; bj = j; }
    int bi = bj * 64 + lane;
    for (int off = 32; off > 0; off >>= 1) {
      const float v2 = __shfl_down(bv, off, 64);
      const int i2 = __shfl_down(bi, off, 64);
      if (v2 > bv || (v2 == bv && i2 < bi)) { bv = v2; bi = i2; }
    }
    bi = __shfl(bi, 0, 64);
    if (lane == 0) idxb[row * KNB + kk] = bi;
    if ((bi & 63) == lane) v[bi >> 6] = -3.4e38f;
  }
}

// ---------------------------------------------------------------------------
// U[b][n][o] = sum_c x[c][n]*Wn[c][o];  Vd = x·Wc − U   (WT rows 0..C-1 = Wn,
// C..2C-1 = Wc).  64n x 64o tile, thread 4n x 4o (o fast for coalesced store).
// ---------------------------------------------------------------------------
template <int C, int O>
__global__ __launch_bounds__(256) void gemm_uv_kernel(
    const float* __restrict__ xbase, int bstr, const float* __restrict__ WT,
    float* __restrict__ U, float* __restrict__ Vd) {
  constexpr int OT = O / 64;
  __shared__ __align__(16) float s_x[8][64];
  __shared__ __align__(16) float s_wn[8][64];
  __shared__ __align__(16) float s_wc[8][64];
  const int t = threadIdx.x;
  const int bx = blockIdx.x;
  const int b = bx / (16 * OT);
  const int r = bx % (16 * OT);
  const int n0 = (r / OT) * 64;
  const int o0 = (r % OT) * 64;
  const float* xb = xbase + (size_t)b * bstr;
  const int tn = (t >> 4) * 4;
  const int to = (t & 15) * 4;
  float accU[4][4] = {}, accC[4][4] = {};
  for (int c0 = 0; c0 < C; c0 += 8) {
    const int kc = (C - c0 < 8) ? (C - c0) : 8;
    for (int i = t; i < 8 * 64; i += 256) {
      const int cc = i >> 6, col = i & 63;
      const bool ok = cc < kc;
      s_x[cc][col]  = ok ? xb[(c0 + cc) * NN + n0 + col] : 0.f;
      s_wn[cc][col] = ok ? WT[(c0 + cc) * O + o0 + col] : 0.f;
      s_wc[cc][col] = ok ? WT[(C + c0 + cc) * O + o0 + col] : 0.f;
    }
    __syncthreads();
#pragma unroll
    for (int cc = 0; cc < 8; ++cc) {
      const float4 xv = *(const float4*)&s_x[cc][tn];
      const float4 wn = *(const float4*)&s_wn[cc][to];
      const float4 wc = *(const float4*)&s_wc[cc][to];
      const float xa[4] = {xv.x, xv.y, xv.z, xv.w};
      const float na[4] = {wn.x, wn.y, wn.z, wn.w};
      const float ca[4] = {wc.x, wc.y, wc.z, wc.w};
#pragma unroll
      for (int i = 0; i < 4; ++i)
#pragma unroll
        for (int j = 0; j < 4; ++j) {
          accU[i][j] = fmaf(xa[i], na[j], accU[i][j]);
          accC[i][j] = fmaf(xa[i], ca[j], accC[i][j]);
        }
    }
    __syncthreads();
  }
#pragma unroll
  for (int i = 0; i < 4; ++i) {
    const size_t base = ((size_t)(b << 10) + n0 + tn + i) * O + o0 + to;
    float4 u4 = make_float4(accU[i][0], accU[i][1], accU[i][2], accU[i][3]);
    float4 v4 = make_float4(accC[i][0] - accU[i][0], accC[i][1] - accU[i][1],
                            accC[i][2] - accU[i][2], accC[i][3] - accU[i][3]);
    *(float4*)&U[base] = u4;
    *(float4*)&Vd[base] = v4;
  }
}

// ---------------------------------------------------------------------------
// edge gather pass: per (b,n,o): y_k = U[b,idx_k,o] + Vd[b,n,o]
// writes ymax/ymin; accumulates BN sums into stats via atomics.
// ---------------------------------------------------------------------------
template <int O>
__global__ __launch_bounds__(256) void edge_pass_kernel(
    const float* __restrict__ U, const float* __restrict__ Vd,
    const int* __restrict__ idxb, float* __restrict__ stats,
    float* __restrict__ ymax, float* __restrict__ ymin) {
  constexpr int PSUB = 256 / O;
  __shared__ float s_red[256];
  const int t = threadIdx.x;
  const int o = t & (O - 1);
  const int psub = t / O;
  float ls1 = 0.f, ls2 = 0.f;
  for (int p = blockIdx.x * PSUB + psub; p < BB * NN; p += gridDim.x * PSUB) {
    const int b = p >> 10;
    const float* ub = U + ((size_t)(b << 10)) * O;
    int id[KNB];
#pragma unroll
    for (int k = 0; k < KNB; ++k) id[k] = idxb[p * KNB + k];
    const float vd = Vd[(size_t)p * O + o];
    float ymx = -3.4e38f, ymn = 3.4e38f;
#pragma unroll
    for (int k = 0; k < KNB; ++k) {
      const float y = ub[(size_t)id[k] * O + o] + vd;
      ymx = fmaxf(ymx, y);
      ymn = fminf(ymn, y);
      ls1 += y;
      ls2 = fmaf(y, y, ls2);
    }
    ymax[(size_t)p * O + o] = ymx;
    ymin[(size_t)p * O + o] = ymn;
  }
  if (PSUB == 1) {
    atomicAdd(&stats[o], ls1);
    atomicAdd(&stats[1024 + o], ls2);
  } else {
    s_red[t] = ls1;
    __syncthreads();
    if (t < O) {
      float s = s_red[t];
#pragma unroll
      for (int p2 = 1; p2 < PSUB; ++p2) s += s_red[t + p2 * O];
      atomicAdd(&stats[t], s);
    }
    __syncthreads();
    s_red[t] = ls2;
    __syncthreads();
    if (t < O) {
      float s = s_red[t];
#pragma unroll
      for (int p2 = 1; p2 < PSUB; ++p2) s += s_red[t + p2 * O];
      atomicAdd(&stats[1024 + t], s);
    }
  }
}

// ---------------------------------------------------------------------------
// finalize BN: scale = g*rsqrt(var+eps), shift = b - mean*scale
// ---------------------------------------------------------------------------
__global__ void bn_finalize_kernel(float* __restrict__ stats,
                                   const float* __restrict__ g,
                                   const float* __restrict__ bb, int cout,
                                   float inv_cnt) {
  const int o = blockIdx.x * 256 + threadIdx.x;
  if (o >= cout) return;
  const float mean = stats[o] * inv_cnt;
  const float var = stats[1024 + o] * inv_cnt - mean * mean;
  const float s = g[o] * rsqrtf(var + BNEPS);
  stats[2048 + o] = s;
  stats[3072 + o] = bb[o] - mean * s;
}

// ---------------------------------------------------------------------------
// bn_apply + transpose: out[b][o][n] = lrelu(sc*(sc>=0?ymax:ymin)+sh)
// 32x32 LDS tile.
// ---------------------------------------------------------------------------
template <int O>
__global__ __launch_bounds__(256) void bn_apply_kernel(
    const float* __restrict__ ymax, const float* __restrict__ ymin,
    const float* __restrict__ stats, float* __restrict__ hout) {
  constexpr int OT = O / 32;
  __shared__ float s_t[32][33];
  const int t = threadIdx.x;
  const int bx = blockIdx.x;
  const int b = bx / (32 * OT);
  const int r = bx % (32 * OT);
  const int n0 = (r / OT) * 32;
  const int o0 = (r % OT) * 32;
  const int col = t & 31, rowb = t >> 5;
  const float sc = stats[2048 + o0 + col];
  const float sh = stats[3072 + o0 + col];
  const float* src = (sc >= 0.f) ? ymax : ymin;
#pragma unroll
  for (int rr = 0; rr < 4; ++rr) {
    const int nl = rowb + rr * 8;
    const float y = src[((size_t)(b << 10) + n0 + nl) * O + o0 + col];
    s_t[nl][col] = lrelu(fmaf(sc, y, sh));
  }
  __syncthreads();
#pragma unroll
  for (int rr = 0; rr < 4; ++rr) {
    const int ol = rowb + rr * 8;
    hout[(size_t)b * (512 * 1024) + (o0 + ol) * NN + n0 + col] = s_t[col][ol];
  }
}

// ---------------------------------------------------------------------------
// conv1d GEMM: Y5[b][o][n] = sum_c WT5[c][o]*h[b][c][n], fused BN stats.
// grid 2048 = b(8) x ot(16) x nt(16); 64o x 64n tile, thread 4o x 4n.
// ---------------------------------------------------------------------------
__global__ __launch_bounds__(256) void conv1d_gemm_kernel(
    const float* __restrict__ hcat, const float* __restrict__ WT5,
    float* __restrict__ stats, float* __restrict__ Y5) {
  __shared__ __align__(16) float s_w[8][64];
  __shared__ __align__(16) float s_h[8][64];
  __shared__ __align__(16) float s_red[64][16];
  const int t = threadIdx.x;
  const int bx = blockIdx.x;
  const int b = bx >> 8;
  const int o0 = ((bx >> 4) & 15) * 64;
  const int n0 = (bx & 15) * 64;
  const float* hb = hcat + (size_t)b * (512 * 1024);
  const int to = (t >> 4) * 4;
  const int tn = (t & 15) * 4;
  float acc[4][4] = {};
  for (int c0 = 0; c0 < 512; c0 += 8) {
    for (int i = t; i < 8 * 64; i += 256) {
      const int cc = i >> 6, col = i & 63;
      s_w[cc][col] = WT5[(c0 + cc) * 1024 + o0 + col];
      s_h[cc][col] = hb[(c0 + cc) * NN + n0 + col];
    }
    __syncthreads();
#pragma unroll
    for (int cc = 0; cc < 8; ++cc) {
      const float4 wv = *(const float4*)&s_w[cc][to];
      const float4 hv = *(const float4*)&s_h[cc][tn];
      const float wa[4] = {wv.x, wv.y, wv.z, wv.w};
      const float ha[4] = {hv.x, hv.y, hv.z, hv.w};
#pragma unroll
      for (int i = 0; i < 4; ++i)
#pragma unroll
        for (int j = 0; j < 4; ++j) acc[i][j] = fmaf(wa[i], ha[j], acc[i][j]);
    }
    __syncthreads();
  }
#pragma unroll
  for (int i = 0; i < 4; ++i) {
    *(float4*)&Y5[((size_t)(b << 10) + o0 + to + i) * NN + n0 + tn] =
        make_float4(acc[i][0], acc[i][1], acc[i][2], acc[i][3]);
  }
  // stats: per-o sums
#pragma unroll
  for (int i = 0; i < 4; ++i)
    s_red[to + i][t & 15] = acc[i][0] + acc[i][1] + acc[i][2] + acc[i][3];
  __syncthreads();
  if (t < 64) {
    float s = 0.f;
#pragma unroll
    for (int g2 = 0; g2 < 16; ++g2) s += s_red[t][g2];
    atomicAdd(&stats[o0 + t], s);
  }
  __syncthreads();
#pragma unroll
  for (int i = 0; i < 4; ++i) {
    float s = 0.f;
#pragma unroll
    for (int j = 0; j < 4; ++j) s = fmaf(acc[i][j], acc[i][j], s);
    s_red[to + i][t & 15] = s;
  }
  __syncthreads();
  if (t < 64) {
    float s = 0.f;
#pragma unroll
    for (int g2 = 0; g2 < 16; ++g2) s += s_red[t][g2];
    atomicAdd(&stats[1024 + o0 + t], s);
  }
}

// ---------------------------------------------------------------------------
// pool: per (b,o): BN+lrelu over n, max & mean -> z[b][2048]
// one wave per o-row; block = 4 rows; grid = 8*256.
// ---------------------------------------------------------------------------
__global__ __launch_bounds__(256) void pool_kernel(
    const float* __restrict__ Y5, const float* __restrict__ stats,
    float* __restrict__ z) {
  const int t = threadIdx.x;
  const int lane = t & 63;
  const int bx = blockIdx.x;
  const int b = bx >> 8;
  const int o = (bx & 255) * 4 + (t >> 6);
  const float sc = stats[2048 + o], sh = stats[3072 + o];
  const float* yr = Y5 + ((size_t)(b << 10) + o) * NN;
  float mx = -3.4e38f, sm = 0.f;
#pragma unroll
  for (int j = 0; j < 16; ++j) {
    const float y = lrelu(fmaf(sc, yr[j * 64 + lane], sh));
    mx = fmaxf(mx, y);
    sm += y;
  }
  for (int off = 32; off > 0; off >>= 1) {
    mx = fmaxf(mx, __shfl_down(mx, off, 64));
    sm += __shfl_down(sm, off, 64);
  }
  if (lane == 0) {
    z[b * 2048 + o] = mx;
    z[b * 2048 + 1024 + o] = sm * (1.f / 1024.f);
  }
}

// ---------------------------------------------------------------------------
// MLP layer with batch-of-8 BN + lrelu fused.
// ---------------------------------------------------------------------------
__global__ __launch_bounds__(256) void mlp_kernel(
    const float* __restrict__ zin, const float* __restrict__ W,
    const float* __restrict__ bias, const float* __restrict__ g,
    const float* __restrict__ bb, int kin, float* __restrict__ out, int O) {
  __shared__ float s_red[256];
  __shared__ float s_y[8];
  const int t = threadIdx.x;
  const int o = blockIdx.x;
  float acc[8];
#pragma unroll
  for (int b = 0; b < 8; ++b) acc[b] = 0.f;
  for (int c = t; c < kin; c += 256) {
    const float w = W[(size_t)o * kin + c];
#pragma unroll
    for (int b = 0; b < 8; ++b) acc[b] = fmaf(w, zin[b * kin + c], acc[b]);
  }
  for (int b = 0; b < 8; ++b) {
    s_red[t] = acc[b];
    __syncthreads();
    for (int s = 128; s > 0; s >>= 1) {
      if (t < s) s_red[t] += s_red[t + s];
      __syncthreads();
    }
    if (t == 0) s_y[b] = s_red[0] + (bias ? bias[o] : 0.f);
    __syncthreads();
  }
  if (t == 0) {
    float m = 0.f;
    for (int b = 0; b < 8; ++b) m += s_y[b];
    m *= 0.125f;
    float v = 0.f;
    for (int b = 0; b < 8; ++b) { const float d = s_y[b] - m; v = fmaf(d, d, v); }
    v *= 0.125f;
    const float s = g[o] * rsqrtf(v + BNEPS);
    const float sh = bb[o] - m * s;
    for (int b = 0; b < 8; ++b) out[b * O + o] = lrelu(fmaf(s, s_y[b], sh));
  }
}

__global__ void final_kernel(const float* __restrict__ z2,
                             const float* __restrict__ Wl3,
                             const float* __restrict__ bl3,
                             const int* __restrict__ flags, void* out) {
  const int j = blockIdx.x * 256 + threadIdx.x;
  if (j >= 320) return;
  const int b = j / 40, o = j - b * 40;
  float s = bl3[o];
  for (int c = 0; c < 256; ++c) s = fmaf(z2[b * 256 + c], Wl3[o * 256 + c], s);
  if (flags[NIN] == 1) ((__hip_bfloat16*)out)[j] = __float2bfloat16(s);
  else ((float*)out)[j] = s;
}

// ---------------------------------------------------------------------------
template <int C, int O>
static void run_stage(float* wsf, const float* xbase, int bstr, int widx,
                      int gidx, int bidx, int stat, float* hout,
                      hipStream_t stream) {
  float* xx = wsf + XXo;
  int* idxb = reinterpret_cast<int*>(wsf + IDXo);
  float* dist = wsf + DISTo;
  float* U = wsf + UOFF;
  float* Vd = wsf + VDOFF;
  float* ymx = wsf + YMXo;
  float* ymn = wsf + YMNo;
  float* stats = wsf + STATSo + stat * 4096;
  xx_kernel<<<32, 256, 0, stream>>>(xbase, bstr, C, xx);
  dist_kernel<C><<<2048, 256, 0, stream>>>(xbase, bstr, xx, dist);
  topk_kernel<<<2048, 256, 0, stream>>>(dist, idxb);
  gemm_uv_kernel<C, O><<<BB * 16 * (O / 64), 256, 0, stream>>>(
      xbase, bstr, wsf + widx, U, Vd);
  edge_pass_kernel<O><<<512, 256, 0, stream>>>(U, Vd, idxb, stats, ymx, ymn);
  bn_finalize_kernel<<<4, 256, 0, stream>>>(stats, wsf + gidx, wsf + bidx, O,
                                            1.f / (8.f * 1024.f * 20.f));
  bn_apply_kernel<O><<<BB * 32 * (O / 32), 256, 0, stream>>>(ymx, ymn, stats,
                                                             hout);
}

extern "C" void kernel_launch(void* const* d_in, const int* in_sizes, int n_in,
                              void* d_out, int out_size, void* d_ws,
                              size_t ws_size, hipStream_t stream) {
  (void)in_sizes; (void)n_in; (void)out_size; (void)ws_size;
  float* wsf = reinterpret_cast<float*>(d_ws);
  int* flags = reinterpret_cast<int*>(wsf + FLAGSo);
  float* hcat = wsf + HCATo;

  Ptrs ptrs;
  for (int i = 0; i < NIN; ++i) ptrs.p[i] = d_in[i];

  detect_kernel<<<NIN, 64, 0, stream>>>(ptrs, flags);
  globalflag_kernel<<<1, 1, 0, stream>>>(flags);
  convert_kernel<<<(TOTAL_IN + 255) / 256, 256, 0, stream>>>(ptrs, flags, wsf);
  zero_kernel<<<80, 256, 0, stream>>>(wsf + STATSo, 20480);

  run_stage<3, 64>(wsf, wsf + XIN, 3 * NN, WT1, G1, B1o, 0, hcat, stream);
  run_stage<64, 64>(wsf, hcat, 512 * NN, WT2, G2, B2o, 1, hcat + 64 * NN,
                    stream);
  run_stage<64, 128>(wsf, hcat + 64 * NN, 512 * NN, WT3, G3, B3o, 2,
                     hcat + 128 * NN, stream);
  run_stage<128, 256>(wsf, hcat + 128 * NN, 512 * NN, WT4, G4, B4o, 3,
                      hcat + 256 * NN, stream);

  // conv1d 512->1024 + BN + pool
  float* Y5 = wsf + Y5o;
  float* st5 = wsf + STATSo + 4 * 4096;
  conv1d_gemm_kernel<<<2048, 256, 0, stream>>>(hcat, wsf + WT5, st5, Y5);
  bn_finalize_kernel<<<4, 256, 0, stream>>>(st5, wsf + G5, wsf + B5o, 1024,
                                            1.f / 8192.f);
  pool_kernel<<<BB * 256, 256, 0, stream>>>(Y5, st5, wsf + Z2048o);

  // MLP head
  mlp_kernel<<<512, 256, 0, stream>>>(wsf + Z2048o, wsf + WL1, nullptr,
      wsf + G6, wsf + B6o, 2048, wsf + Z1o, 512);
  mlp_kernel<<<256, 256, 0, stream>>>(wsf + Z1o, wsf + WL2, wsf + BL2o,
      wsf + G7, wsf + B7o, 512, wsf + Z2o, 256);
  final_kernel<<<2, 256, 0, stream>>>(wsf + Z2o, wsf + WL3, wsf + BL3o,
      flags, d_out);
}

// Round 5
// 712.352 us; speedup vs baseline: 4.4109x; 1.0923x over previous
//
#include <hip/hip_runtime.h>
#include <hip/hip_bf16.h>
#include <cstdint>

// ---------------------------------------------------------------------------
// DGCNN forward on MI355X. Math f32; conv1d via bf16 MFMA (inputs bf16-safe).
// R5: conv1d -> mfma_f32_32x32x16_bf16; dist 8x8 register tile; BN finalize
// inlined; kNN/dist kept f32 (selection stability).
// ---------------------------------------------------------------------------

static constexpr int BB  = 8;
static constexpr int NN  = 1024;
static constexpr int KNB = 20;
static constexpr float BNEPS = 1e-5f;

static constexpr int NIN = 25;

__constant__ int c_cum[NIN + 1] = {
    0, 24576, 24960, 33152, 49536, 115072, 639360,
    1687936, 1819008, 1819264, 1829504, 1829544, 1829608, 1829672, 1829736,
    1829800, 1829928, 1830056, 1830312, 1830568, 1831592, 1832616, 1833128,
    1833640, 1833896, 1834152};
__constant__ int c_trO[NIN] = {0, 64, 64, 128, 256, 1024, 0, 0, 0, 0, 0,
                               0, 0, 0, 0, 0, 0, 0, 0, 0, 0, 0, 0, 0, 0};
__constant__ int c_trI[NIN] = {0, 6, 128, 128, 256, 512, 0, 0, 0, 0, 0,
                               0, 0, 0, 0, 0, 0, 0, 0, 0, 0, 0, 0, 0, 0};

enum : int {
  XIN = 0, WT1 = 24576, WT2 = 24960, WT3 = 33152, WT4 = 49536, WT5 = 115072,
  WL1 = 639360, WL2 = 1687936, BL2o = 1819008, WL3 = 1819264, BL3o = 1829504,
  G1 = 1829544, B1o = 1829608, G2 = 1829672, B2o = 1829736,
  G3 = 1829800, B3o = 1829928, G4 = 1830056, B4o = 1830312,
  G5 = 1830568, B5o = 1831592, G6 = 1832616, B6o = 1833128,
  G7 = 1833640, B7o = 1833896,
  XXo = 1834240,        // 8192 f
  IDXo = 1842432,       // 163840 i32
  HCATo = 2006272,      // 8*512*1024 f
  STATSo = 6200576,     // 5 layers * 4096 f (sum, sumsq, scale, shift)
  Z2048o = 6237440,     // 8*2048 f
  Z1o = 6253824,        // 8*512 f
  Z2o = 6257920,        // 8*256 f
  FLAGSo = 6259968,     // 32 i32
  DISTo = 6260736,      // 8M floats window: dist / {U,Vd,ymax,ymin} / Y5
  HBFo  = 14649344,     // 8*1024*512 bf16 (2M float slots)
  W5BFo = 16746496      // 1024*512 bf16 (262144 float slots) -> ends 17008640
};
static constexpr int TOTAL_IN = 1834152;
enum : int {
  UOFF  = DISTo + 0,
  VDOFF = DISTo + 2097152,
  YMXo  = DISTo + 4194304,
  YMNo  = DISTo + 6291456,
  Y5o   = DISTo + 0
};
static constexpr size_t WS_NEED_MFMA = (size_t)17008640 * 4;  // ~68 MB

struct Ptrs { const void* p[NIN]; };

typedef short short8v __attribute__((ext_vector_type(8)));
typedef float f32x16 __attribute__((ext_vector_type(16)));

__device__ __forceinline__ float lrelu(float y) { return (y < 0.f) ? 0.2f * y : y; }
__device__ __forceinline__ unsigned short f2b(float f) {
  unsigned u = __float_as_uint(f);
  unsigned r = (u + 0x7FFFu + ((u >> 16) & 1u)) >> 16;   // RNE
  return (unsigned short)r;
}

// ---------------------------------------------------------------------------
// dtype detection / conversion
// ---------------------------------------------------------------------------
__global__ void detect_kernel(Ptrs ptrs, int* __restrict__ flags) {
  const int i = blockIdx.x;
  const unsigned* p = (const unsigned*)ptrs.p[i];
  const int n = c_cum[i + 1] - c_cum[i];
  int words = n >> 1; if (words > 64) words = 64;
  const int t = threadIdx.x;
  unsigned w = (t < words) ? p[t] : 0u;
  bool nz = (w != 0u);
  unsigned e = (w >> 7) & 0xFFu;
  bool pl = nz && (e >= 96u) && (e <= 140u);
  unsigned long long mnz = __ballot(nz);
  unsigned long long mpl = __ballot(pl);
  if (t == 0) {
    int cnz = __popcll(mnz), cpl = __popcll(mpl);
    flags[i] = (cnz == 0) ? 2 : ((2 * cpl > words) ? 1 : 0);
  }
}

__global__ void globalflag_kernel(int* __restrict__ flags) {
  int anyf32 = 0, anybf = 0;
  for (int i = 0; i < NIN; ++i) {
    if (flags[i] == 0) anyf32 = 1;
    if (flags[i] == 1) anybf = 1;
  }
  flags[NIN] = (anybf && !anyf32) ? 1 : 0;
}

__global__ void convert_kernel(Ptrs ptrs, const int* __restrict__ flags,
                               float* __restrict__ ws) {
  const int e = blockIdx.x * 256 + threadIdx.x;
  if (e >= TOTAL_IN) return;
  int i = 0;
  while (e >= c_cum[i + 1]) ++i;
  const int el = e - c_cum[i];
  int src;
  const int O = c_trO[i];
  if (O > 0) {
    const int I = c_trI[i];
    const int o = el % O, ii = el / O;
    src = o * I + ii;
  } else src = el;
  float v;
  const int fl = flags[i];
  if (fl == 2) v = 0.f;
  else if (fl == 1) {
    const unsigned short u = ((const unsigned short*)ptrs.p[i])[src];
    v = __uint_as_float(((unsigned)u) << 16);
  } else v = ((const float*)ptrs.p[i])[src];
  ws[e] = v;
}

// WT5 [c][o] f32 -> w5bf [o][c] bf16 via 32x32 LDS transpose tiles
__global__ __launch_bounds__(256) void w5prep_kernel(
    const float* __restrict__ WT5, unsigned short* __restrict__ wbf) {
  __shared__ float s[32][33];
  const int t = threadIdx.x, bx = blockIdx.x;
  const int co0 = (bx & 15) * 32;        // 512/32
  const int oo0 = (bx >> 4) * 32;        // 1024/32
  const int col = t & 31, row = t >> 5;
#pragma unroll
  for (int rr = 0; rr < 4; ++rr) {
    const int c = co0 + row + rr * 8;
    s[row + rr * 8][col] = WT5[(size_t)c * 1024 + oo0 + col];
  }
  __syncthreads();
#pragma unroll
  for (int rr = 0; rr < 4; ++rr) {
    const int o = oo0 + row + rr * 8;
    wbf[(size_t)o * 512 + co0 + col] = f2b(s[col][row + rr * 8]);
  }
}

__global__ void zero_kernel(float* __restrict__ p, int n) {
  const int i = blockIdx.x * 256 + threadIdx.x;
  if (i < n) p[i] = 0.f;
}

// ---------------------------------------------------------------------------
// xx[b][n] = sum_c x[b][c][n]^2
// ---------------------------------------------------------------------------
__global__ void xx_kernel(const float* __restrict__ xbase, int bstr, int C,
                          float* __restrict__ xx) {
  const int i = blockIdx.x * 256 + threadIdx.x;
  if (i >= BB * NN) return;
  const int b = i >> 10, n = i & 1023;
  const float* xb = xbase + (size_t)b * bstr;
  float s = 0.f;
  for (int c = 0; c < C; ++c) { const float v = xb[c * NN + n]; s = fmaf(v, v, s); }
  xx[i] = s;
}

// ---------------------------------------------------------------------------
// dist GEMM 8x8 reg tile: D[b][n][m] = 2*dot - xx[n] - xx[m]
// 128x128 block tile, 512 blocks (8b x 8 x 8).
// ---------------------------------------------------------------------------
template <int C>
__global__ __launch_bounds__(256) void dist2_kernel(
    const float* __restrict__ xbase, int bstr, const float* __restrict__ xx,
    float* __restrict__ D) {
  __shared__ __align__(16) float s_a[16][128];
  __shared__ __align__(16) float s_b[16][128];
  const int t = threadIdx.x;
  const int bx = blockIdx.x;
  const int b = bx >> 6;
  const int r = bx & 63;
  const int tn0 = (r >> 3) * 128;
  const int tm0 = (r & 7) * 128;
  const float* xb = xbase + (size_t)b * bstr;
  const int tn = (t >> 4) * 8;
  const int tm = (t & 15) * 8;
  float acc[8][8] = {};
  for (int c0 = 0; c0 < C; c0 += 16) {
    const int kc = (C - c0 < 16) ? (C - c0) : 16;
    for (int i = t; i < 512; i += 256) {
      const int cc = i >> 5, col4 = (i & 31) * 4;
      float4 va = make_float4(0.f, 0.f, 0.f, 0.f), vb = va;
      if (cc < kc) {
        va = *(const float4*)&xb[(c0 + cc) * NN + tn0 + col4];
        vb = *(const float4*)&xb[(c0 + cc) * NN + tm0 + col4];
      }
      *(float4*)&s_a[cc][col4] = va;
      *(float4*)&s_b[cc][col4] = vb;
    }
    __syncthreads();
#pragma unroll
    for (int cc = 0; cc < 16; ++cc) {
      const float4 a0 = *(const float4*)&s_a[cc][tn];
      const float4 a1 = *(const float4*)&s_a[cc][tn + 4];
      const float4 b0 = *(const float4*)&s_b[cc][tm];
      const float4 b1 = *(const float4*)&s_b[cc][tm + 4];
      const float aa[8] = {a0.x, a0.y, a0.z, a0.w, a1.x, a1.y, a1.z, a1.w};
      const float bb2[8] = {b0.x, b0.y, b0.z, b0.w, b1.x, b1.y, b1.z, b1.w};
#pragma unroll
      for (int i = 0; i < 8; ++i)
#pragma unroll
        for (int j = 0; j < 8; ++j) acc[i][j] = fmaf(aa[i], bb2[j], acc[i][j]);
    }
    __syncthreads();
  }
  const float4 xm0 = *(const float4*)&xx[(b << 10) + tm0 + tm];
  const float4 xm1 = *(const float4*)&xx[(b << 10) + tm0 + tm + 4];
  const float xmv[8] = {xm0.x, xm0.y, xm0.z, xm0.w, xm1.x, xm1.y, xm1.z, xm1.w};
  float* Db = D + ((size_t)b << 20);
#pragma unroll
  for (int i = 0; i < 8; ++i) {
    const float xxn = xx[(b << 10) + tn0 + tn + i];
    float4 o0v, o1v;
    o0v.x = 2.f * acc[i][0] - xxn - xmv[0];
    o0v.y = 2.f * acc[i][1] - xxn - xmv[1];
    o0v.z = 2.f * acc[i][2] - xxn - xmv[2];
    o0v.w = 2.f * acc[i][3] - xxn - xmv[3];
    o1v.x = 2.f * acc[i][4] - xxn - xmv[4];
    o1v.y = 2.f * acc[i][5] - xxn - xmv[5];
    o1v.z = 2.f * acc[i][6] - xxn - xmv[6];
    o1v.w = 2.f * acc[i][7] - xxn - xmv[7];
    float* row = &Db[(size_t)(tn0 + tn + i) * NN + tm0 + tm];
    *(float4*)row = o0v;
    *(float4*)(row + 4) = o1v;
  }
}

// top-20 per row; one wave per row; tie -> lower index (matches lax.top_k)
__global__ __launch_bounds__(256) void topk_kernel(const float* __restrict__ D,
                                                   int* __restrict__ idxb) {
  const int t = threadIdx.x;
  const int lane = t & 63;
  const int row = blockIdx.x * 4 + (t >> 6);
  const float* Dr = D + ((size_t)row << 10);
  float v[16];
#pragma unroll
  for (int j = 0; j < 16; ++j) v[j] = Dr[j * 64 + lane];
  for (int kk = 0; kk < KNB; ++kk) {
    float bv = v[0]; int bj = 0;
#pragma unroll
    for (int j = 1; j < 16; ++j)
      if (v[j] > bv) { bv = v[j]; bj = j; }
    int bi = bj * 64 + lane;
    for (int off = 32; off > 0; off >>= 1) {
      const float v2 = __shfl_down(bv, off, 64);
      const int i2 = __shfl_down(bi, off, 64);
      if (v2 > bv || (v2 == bv && i2 < bi)) { bv = v2; bi = i2; }
    }
    bi = __shfl(bi, 0, 64);
    if (lane == 0) idxb[row * KNB + kk] = bi;
    if ((bi & 63) == lane) v[bi >> 6] = -3.4e38f;
  }
}

// ---------------------------------------------------------------------------
// U[b][n][o] = x·Wn ; Vd = x·Wc − U   (WT rows 0..C-1 = Wn, C..2C-1 = Wc)
// ---------------------------------------------------------------------------
template <int C, int O>
__global__ __launch_bounds__(256) void gemm_uv_kernel(
    const float* __restrict__ xbase, int bstr, const float* __restrict__ WT,
    float* __restrict__ U, float* __restrict__ Vd) {
  constexpr int OT = O / 64;
  __shared__ __align__(16) float s_x[8][64];
  __shared__ __align__(16) float s_wn[8][64];
  __shared__ __align__(16) float s_wc[8][64];
  const int t = threadIdx.x;
  const int bx = blockIdx.x;
  const int b = bx / (16 * OT);
  const int r = bx % (16 * OT);
  const int n0 = (r / OT) * 64;
  const int o0 = (r % OT) * 64;
  const float* xb = xbase + (size_t)b * bstr;
  const int tn = (t >> 4) * 4;
  const int to = (t & 15) * 4;
  float accU[4][4] = {}, accC[4][4] = {};
  for (int c0 = 0; c0 < C; c0 += 8) {
    const int kc = (C - c0 < 8) ? (C - c0) : 8;
    for (int i = t; i < 8 * 64; i += 256) {
      const int cc = i >> 6, col = i & 63;
      const bool ok = cc < kc;
      s_x[cc][col]  = ok ? xb[(c0 + cc) * NN + n0 + col] : 0.f;
      s_wn[cc][col] = ok ? WT[(c0 + cc) * O + o0 + col] : 0.f;
      s_wc[cc][col] = ok ? WT[(C + c0 + cc) * O + o0 + col] : 0.f;
    }
    __syncthreads();
#pragma unroll
    for (int cc = 0; cc < 8; ++cc) {
      const float4 xv = *(const float4*)&s_x[cc][tn];
      const float4 wn = *(const float4*)&s_wn[cc][to];
      const float4 wc = *(const float4*)&s_wc[cc][to];
      const float xa[4] = {xv.x, xv.y, xv.z, xv.w};
      const float na[4] = {wn.x, wn.y, wn.z, wn.w};
      const float ca[4] = {wc.x, wc.y, wc.z, wc.w};
#pragma unroll
      for (int i = 0; i < 4; ++i)
#pragma unroll
        for (int j = 0; j < 4; ++j) {
          accU[i][j] = fmaf(xa[i], na[j], accU[i][j]);
          accC[i][j] = fmaf(xa[i], ca[j], accC[i][j]);
        }
    }
    __syncthreads();
  }
#pragma unroll
  for (int i = 0; i < 4; ++i) {
    const size_t base = ((size_t)(b << 10) + n0 + tn + i) * O + o0 + to;
    *(float4*)&U[base] = make_float4(accU[i][0], accU[i][1], accU[i][2], accU[i][3]);
    *(float4*)&Vd[base] = make_float4(accC[i][0] - accU[i][0], accC[i][1] - accU[i][1],
                                      accC[i][2] - accU[i][2], accC[i][3] - accU[i][3]);
  }
}

// ---------------------------------------------------------------------------
// edge gather pass: y_k = U[b,idx_k,o] + Vd[b,n,o]; ymax/ymin + BN sums.
// ---------------------------------------------------------------------------
template <int O>
__global__ __launch_bounds__(256) void edge_pass_kernel(
    const float* __restrict__ U, const float* __restrict__ Vd,
    const int* __restrict__ idxb, float* __restrict__ stats,
    float* __restrict__ ymax, float* __restrict__ ymin) {
  constexpr int PSUB = 256 / O;
  __shared__ float s_red[256];
  const int t = threadIdx.x;
  const int o = t & (O - 1);
  const int psub = t / O;
  float ls1 = 0.f, ls2 = 0.f;
  for (int p = blockIdx.x * PSUB + psub; p < BB * NN; p += gridDim.x * PSUB) {
    const int b = p >> 10;
    const float* ub = U + ((size_t)(b << 10)) * O;
    int id[KNB];
#pragma unroll
    for (int k = 0; k < KNB; ++k) id[k] = idxb[p * KNB + k];
    const float vd = Vd[(size_t)p * O + o];
    float ymx = -3.4e38f, ymn = 3.4e38f;
#pragma unroll
    for (int k = 0; k < KNB; ++k) {
      const float y = ub[(size_t)id[k] * O + o] + vd;
      ymx = fmaxf(ymx, y);
      ymn = fminf(ymn, y);
      ls1 += y;
      ls2 = fmaf(y, y, ls2);
    }
    ymax[(size_t)p * O + o] = ymx;
    ymin[(size_t)p * O + o] = ymn;
  }
  if (PSUB == 1) {
    atomicAdd(&stats[o], ls1);
    atomicAdd(&stats[1024 + o], ls2);
  } else {
    s_red[t] = ls1;
    __syncthreads();
    if (t < O) {
      float s = s_red[t];
#pragma unroll
      for (int p2 = 1; p2 < PSUB; ++p2) s += s_red[t + p2 * O];
      atomicAdd(&stats[t], s);
    }
    __syncthreads();
    s_red[t] = ls2;
    __syncthreads();
    if (t < O) {
      float s = s_red[t];
#pragma unroll
      for (int p2 = 1; p2 < PSUB; ++p2) s += s_red[t + p2 * O];
      atomicAdd(&stats[1024 + t], s);
    }
  }
}

// ---------------------------------------------------------------------------
// bn_apply (finalize inlined) + transpose; optional bf16 [n][c] copy for MFMA.
// ---------------------------------------------------------------------------
template <int O>
__global__ __launch_bounds__(256) void bn_apply_kernel(
    const float* __restrict__ ymax, const float* __restrict__ ymin,
    const float* __restrict__ stats, const float* __restrict__ g,
    const float* __restrict__ bb, float* __restrict__ hout,
    unsigned short* __restrict__ hbf, int coff) {
  constexpr int OT = O / 32;
  __shared__ float s_t[32][33];
  const int t = threadIdx.x;
  const int bx = blockIdx.x;
  const int b = bx / (32 * OT);
  const int r = bx % (32 * OT);
  const int n0 = (r / OT) * 32;
  const int o0 = (r % OT) * 32;
  const int col = t & 31, rowb = t >> 5;
  const int o = o0 + col;
  const float inv = 1.f / (8.f * 1024.f * 20.f);
  const float mean = stats[o] * inv;
  const float var = stats[1024 + o] * inv - mean * mean;
  const float sc = g[o] * rsqrtf(var + BNEPS);
  const float sh = bb[o] - mean * sc;
  const float* src = (sc >= 0.f) ? ymax : ymin;
#pragma unroll
  for (int rr = 0; rr < 4; ++rr) {
    const int nl = rowb + rr * 8;
    const float y = src[((size_t)(b << 10) + n0 + nl) * O + o0 + col];
    const float h = lrelu(fmaf(sc, y, sh));
    s_t[nl][col] = h;
    if (hbf)
      hbf[((size_t)(b << 10) + n0 + nl) * 512 + coff + o0 + col] = f2b(h);
  }
  __syncthreads();
#pragma unroll
  for (int rr = 0; rr < 4; ++rr) {
    const int ol = rowb + rr * 8;
    hout[(size_t)b * (512 * 1024) + (o0 + ol) * NN + n0 + col] = s_t[col][ol];
  }
}

// ---------------------------------------------------------------------------
// conv1d via MFMA: Y5[b][o][n] = sum_c W5[o][c]*h[b][n][c]  (both bf16)
// block 64o x 64n, 4 waves each 32x32; K=512 in steps of 16.
// ---------------------------------------------------------------------------
__global__ __launch_bounds__(256) void conv1d_mfma_kernel(
    const unsigned short* __restrict__ hbf,
    const unsigned short* __restrict__ w5bf, float* __restrict__ Y5) {
  const int t = threadIdx.x, bx = blockIdx.x;
  const int b = bx >> 8;
  const int o0 = ((bx >> 4) & 15) * 64;
  const int n0 = (bx & 15) * 64;
  const int wave = t >> 6, lane = t & 63;
  const int oh = (wave & 1) * 32, nh = (wave >> 1) * 32;
  const int l31 = lane & 31, l5 = lane >> 5;
  const unsigned short* ap = w5bf + (size_t)(o0 + oh + l31) * 512 + l5 * 8;
  const unsigned short* bp =
      hbf + ((size_t)((b << 10) + n0 + nh + l31)) * 512 + l5 * 8;
  f32x16 acc;
#pragma unroll
  for (int i = 0; i < 16; ++i) acc[i] = 0.f;
#pragma unroll 4
  for (int k0 = 0; k0 < 512; k0 += 16) {
    const short8v av = *(const short8v*)(ap + k0);
    const short8v bv = *(const short8v*)(bp + k0);
    acc = __builtin_amdgcn_mfma_f32_32x32x16_bf16(av, bv, acc, 0, 0, 0);
  }
  float* yb = Y5 + ((size_t)(b << 10) + o0 + oh) * 1024 + n0 + nh;
#pragma unroll
  for (int r = 0; r < 16; ++r) {
    const int row = (r & 3) + 8 * (r >> 2) + 4 * l5;
    yb[(size_t)row * 1024 + l31] = acc[r];
  }
}

// conv1d BN stats + finalize (no atomics): one block per output channel o.
__global__ __launch_bounds__(256) void c1stats_kernel(
    const float* __restrict__ Y5, const float* __restrict__ g,
    const float* __restrict__ bb, float* __restrict__ stats) {
  __shared__ float sr[256];
  const int o = blockIdx.x, t = threadIdx.x;
  float s1 = 0.f, s2 = 0.f;
  for (int b = 0; b < 8; ++b) {
    const float* yr = Y5 + ((size_t)((b << 10) + o)) * 1024;
    for (int j = t; j < 1024; j += 256) {
      const float v = yr[j];
      s1 += v;
      s2 = fmaf(v, v, s2);
    }
  }
  sr[t] = s1;
  __syncthreads();
  for (int s = 128; s > 0; s >>= 1) {
    if (t < s) sr[t] += sr[t + s];
    __syncthreads();
  }
  float tot1 = 0.f;
  if (t == 0) tot1 = sr[0];
  __syncthreads();
  sr[t] = s2;
  __syncthreads();
  for (int s = 128; s > 0; s >>= 1) {
    if (t < s) sr[t] += sr[t + s];
    __syncthreads();
  }
  if (t == 0) {
    const float mean = tot1 * (1.f / 8192.f);
    const float var = sr[0] * (1.f / 8192.f) - mean * mean;
    const float sc = g[o] * rsqrtf(var + BNEPS);
    stats[2048 + o] = sc;
    stats[3072 + o] = bb[o] - mean * sc;
  }
}

// ---------------------------------------------------------------------------
// fallback f32 conv1d (used only if ws too small for MFMA buffers)
// ---------------------------------------------------------------------------
__global__ void bn_finalize_kernel(float* __restrict__ stats,
                                   const float* __restrict__ g,
                                   const float* __restrict__ bb, int cout,
                                   float inv_cnt) {
  const int o = blockIdx.x * 256 + threadIdx.x;
  if (o >= cout) return;
  const float mean = stats[o] * inv_cnt;
  const float var = stats[1024 + o] * inv_cnt - mean * mean;
  const float s = g[o] * rsqrtf(var + BNEPS);
  stats[2048 + o] = s;
  stats[3072 + o] = bb[o] - mean * s;
}

__global__ __launch_bounds__(256) void conv1d_gemm_kernel(
    const float* __restrict__ hcat, const float* __restrict__ WT5,
    float* __restrict__ stats, float* __restrict__ Y5) {
  __shared__ __align__(16) float s_w[8][64];
  __shared__ __align__(16) float s_h[8][64];
  __shared__ __align__(16) float s_red[64][16];
  const int t = threadIdx.x;
  const int bx = blockIdx.x;
  const int b = bx >> 8;
  const int o0 = ((bx >> 4) & 15) * 64;
  const int n0 = (bx & 15) * 64;
  const float* hb = hcat + (size_t)b * (512 * 1024);
  const int to = (t >> 4) * 4;
  const int tn = (t & 15) * 4;
  float acc[4][4] = {};
  for (int c0 = 0; c0 < 512; c0 += 8) {
    for (int i = t; i < 8 * 64; i += 256) {
      const int cc = i >> 6, col = i & 63;
      s_w[cc][col] = WT5[(c0 + cc) * 1024 + o0 + col];
      s_h[cc][col] = hb[(c0 + cc) * NN + n0 + col];
    }
    __syncthreads();
#pragma unroll
    for (int cc = 0; cc < 8; ++cc) {
      const float4 wv = *(const float4*)&s_w[cc][to];
      const float4 hv = *(const float4*)&s_h[cc][tn];
      const float wa[4] = {wv.x, wv.y, wv.z, wv.w};
      const float ha[4] = {hv.x, hv.y, hv.z, hv.w};
#pragma unroll
      for (int i = 0; i < 4; ++i)
#pragma unroll
        for (int j = 0; j < 4; ++j) acc[i][j] = fmaf(wa[i], ha[j], acc[i][j]);
    }
    __syncthreads();
  }
#pragma unroll
  for (int i = 0; i < 4; ++i) {
    *(float4*)&Y5[((size_t)(b << 10) + o0 + to + i) * NN + n0 + tn] =
        make_float4(acc[i][0], acc[i][1], acc[i][2], acc[i][3]);
  }
#pragma unroll
  for (int i = 0; i < 4; ++i)
    s_red[to + i][t & 15] = acc[i][0] + acc[i][1] + acc[i][2] + acc[i][3];
  __syncthreads();
  if (t < 64) {
    float s = 0.f;
#pragma unroll
    for (int g2 = 0; g2 < 16; ++g2) s += s_red[t][g2];
    atomicAdd(&stats[o0 + t], s);
  }
  __syncthreads();
#pragma unroll
  for (int i = 0; i < 4; ++i) {
    float s = 0.f;
#pragma unroll
    for (int j = 0; j < 4; ++j) s = fmaf(acc[i][j], acc[i][j], s);
    s_red[to + i][t & 15] = s;
  }
  __syncthreads();
  if (t < 64) {
    float s = 0.f;
#pragma unroll
    for (int g2 = 0; g2 < 16; ++g2) s += s_red[t][g2];
    atomicAdd(&stats[1024 + o0 + t], s);
  }
}

// ---------------------------------------------------------------------------
// pool: per (b,o): BN+lrelu over n, max & mean -> z[b][2048]
// ---------------------------------------------------------------------------
__global__ __launch_bounds__(256) void pool_kernel(
    const float* __restrict__ Y5, const float* __restrict__ stats,
    float* __restrict__ z) {
  const int t = threadIdx.x;
  const int lane = t & 63;
  const int bx = blockIdx.x;
  const int b = bx >> 8;
  const int o = (bx & 255) * 4 + (t >> 6);
  const float sc = stats[2048 + o], sh = stats[3072 + o];
  const float* yr = Y5 + ((size_t)(b << 10) + o) * NN;
  float mx = -3.4e38f, sm = 0.f;
#pragma unroll
  for (int j = 0; j < 16; ++j) {
    const float y = lrelu(fmaf(sc, yr[j * 64 + lane], sh));
    mx = fmaxf(mx, y);
    sm += y;
  }
  for (int off = 32; off > 0; off >>= 1) {
    mx = fmaxf(mx, __shfl_down(mx, off, 64));
    sm += __shfl_down(sm, off, 64);
  }
  if (lane == 0) {
    z[b * 2048 + o] = mx;
    z[b * 2048 + 1024 + o] = sm * (1.f / 1024.f);
  }
}

// ---------------------------------------------------------------------------
// MLP layer with batch-of-8 BN + lrelu fused.
// ---------------------------------------------------------------------------
__global__ __launch_bounds__(256) void mlp_kernel(
    const float* __restrict__ zin, const float* __restrict__ W,
    const float* __restrict__ bias, const float* __restrict__ g,
    const float* __restrict__ bb, int kin, float* __restrict__ out, int O) {
  __shared__ float s_red[256];
  __shared__ float s_y[8];
  const int t = threadIdx.x;
  const int o = blockIdx.x;
  float acc[8];
#pragma unroll
  for (int b = 0; b < 8; ++b) acc[b] = 0.f;
  for (int c = t; c < kin; c += 256) {
    const float w = W[(size_t)o * kin + c];
#pragma unroll
    for (int b = 0; b < 8; ++b) acc[b] = fmaf(w, zin[b * kin + c], acc[b]);
  }
  for (int b = 0; b < 8; ++b) {
    s_red[t] = acc[b];
    __syncthreads();
    for (int s = 128; s > 0; s >>= 1) {
      if (t < s) s_red[t] += s_red[t + s];
      __syncthreads();
    }
    if (t == 0) s_y[b] = s_red[0] + (bias ? bias[o] : 0.f);
    __syncthreads();
  }
  if (t == 0) {
    float m = 0.f;
    for (int b = 0; b < 8; ++b) m += s_y[b];
    m *= 0.125f;
    float v = 0.f;
    for (int b = 0; b < 8; ++b) { const float d = s_y[b] - m; v = fmaf(d, d, v); }
    v *= 0.125f;
    const float s = g[o] * rsqrtf(v + BNEPS);
    const float sh = bb[o] - m * s;
    for (int b = 0; b < 8; ++b) out[b * O + o] = lrelu(fmaf(s, s_y[b], sh));
  }
}

__global__ void final_kernel(const float* __restrict__ z2,
                             const float* __restrict__ Wl3,
                             const float* __restrict__ bl3,
                             const int* __restrict__ flags, void* out) {
  const int j = blockIdx.x * 256 + threadIdx.x;
  if (j >= 320) return;
  const int b = j / 40, o = j - b * 40;
  float s = bl3[o];
  for (int c = 0; c < 256; ++c) s = fmaf(z2[b * 256 + c], Wl3[o * 256 + c], s);
  if (flags[NIN] == 1) ((__hip_bfloat16*)out)[j] = __float2bfloat16(s);
  else ((float*)out)[j] = s;
}

// ---------------------------------------------------------------------------
template <int C, int O>
static void run_stage(float* wsf, const float* xbase, int bstr, int widx,
                      int gidx, int bidx, int stat, float* hout,
                      unsigned short* hbf, int coff, hipStream_t stream) {
  float* xx = wsf + XXo;
  int* idxb = reinterpret_cast<int*>(wsf + IDXo);
  float* dist = wsf + DISTo;
  float* U = wsf + UOFF;
  float* Vd = wsf + VDOFF;
  float* ymx = wsf + YMXo;
  float* ymn = wsf + YMNo;
  float* stats = wsf + STATSo + stat * 4096;
  xx_kernel<<<32, 256, 0, stream>>>(xbase, bstr, C, xx);
  dist2_kernel<C><<<512, 256, 0, stream>>>(xbase, bstr, xx, dist);
  topk_kernel<<<2048, 256, 0, stream>>>(dist, idxb);
  gemm_uv_kernel<C, O><<<BB * 16 * (O / 64), 256, 0, stream>>>(
      xbase, bstr, wsf + widx, U, Vd);
  edge_pass_kernel<O><<<512, 256, 0, stream>>>(U, Vd, idxb, stats, ymx, ymn);
  bn_apply_kernel<O><<<BB * 32 * (O / 32), 256, 0, stream>>>(
      ymx, ymn, stats, wsf + gidx, wsf + bidx, hout, hbf, coff);
}

extern "C" void kernel_launch(void* const* d_in, const int* in_sizes, int n_in,
                              void* d_out, int out_size, void* d_ws,
                              size_t ws_size, hipStream_t stream) {
  (void)in_sizes; (void)n_in; (void)out_size;
  float* wsf = reinterpret_cast<float*>(d_ws);
  int* flags = reinterpret_cast<int*>(wsf + FLAGSo);
  float* hcat = wsf + HCATo;
  const bool mf = ws_size >= WS_NEED_MFMA;
  unsigned short* hbf = mf ? reinterpret_cast<unsigned short*>(wsf + HBFo) : nullptr;
  unsigned short* w5bf = reinterpret_cast<unsigned short*>(wsf + W5BFo);

  Ptrs ptrs;
  for (int i = 0; i < NIN; ++i) ptrs.p[i] = d_in[i];

  detect_kernel<<<NIN, 64, 0, stream>>>(ptrs, flags);
  globalflag_kernel<<<1, 1, 0, stream>>>(flags);
  convert_kernel<<<(TOTAL_IN + 255) / 256, 256, 0, stream>>>(ptrs, flags, wsf);
  if (mf) w5prep_kernel<<<512, 256, 0, stream>>>(wsf + WT5, w5bf);
  zero_kernel<<<80, 256, 0, stream>>>(wsf + STATSo, 20480);

  run_stage<3, 64>(wsf, wsf + XIN, 3 * NN, WT1, G1, B1o, 0, hcat, hbf, 0,
                   stream);
  run_stage<64, 64>(wsf, hcat, 512 * NN, WT2, G2, B2o, 1, hcat + 64 * NN, hbf,
                    64, stream);
  run_stage<64, 128>(wsf, hcat + 64 * NN, 512 * NN, WT3, G3, B3o, 2,
                     hcat + 128 * NN, hbf, 128, stream);
  run_stage<128, 256>(wsf, hcat + 128 * NN, 512 * NN, WT4, G4, B4o, 3,
                      hcat + 256 * NN, hbf, 256, stream);

  // conv1d 512->1024 + BN + pool
  float* Y5 = wsf + Y5o;
  float* st5 = wsf + STATSo + 4 * 4096;
  if (mf) {
    conv1d_mfma_kernel<<<2048, 256, 0, stream>>>(hbf, w5bf, Y5);
    c1stats_kernel<<<1024, 256, 0, stream>>>(Y5, wsf + G5, wsf + B5o, st5);
  } else {
    conv1d_gemm_kernel<<<2048, 256, 0, stream>>>(hcat, wsf + WT5, st5, Y5);
    bn_finalize_kernel<<<4, 256, 0, stream>>>(st5, wsf + G5, wsf + B5o, 1024,
                                              1.f / 8192.f);
  }
  pool_kernel<<<BB * 256, 256, 0, stream>>>(Y5, st5, wsf + Z2048o);

  // MLP head
  mlp_kernel<<<512, 256, 0, stream>>>(wsf + Z2048o, wsf + WL1, nullptr,
      wsf + G6, wsf + B6o, 2048, wsf + Z1o, 512);
  mlp_kernel<<<256, 256, 0, stream>>>(wsf + Z1o, wsf + WL2, wsf + BL2o,
      wsf + G7, wsf + B7o, 512, wsf + Z2o, 256);
  final_kernel<<<2, 256, 0, stream>>>(wsf + Z2o, wsf + WL3, wsf + BL3o,
      flags, d_out);
}